// Round 2
// baseline (1259.234 us; speedup 1.0000x reference)
//
#include <hip/hip_runtime.h>

// Problem constants: B=2, S=2048, D_IN=D_OUT=4096, H=32, G=8, HD=128, GS=4
// All matmuls are C[M,N] = A[M,K] @ B[N,K]^T ("gemm_bt", K contiguous in both).

typedef float f32x4 __attribute__((ext_vector_type(4)));
typedef short s16x8 __attribute__((ext_vector_type(8)));

union U8 { s16x8 v; unsigned int u[4]; };

__device__ __forceinline__ unsigned short f32_to_bf16(float f) {
    unsigned int u = __float_as_uint(f);
    u += 0x7fffu + ((u >> 16) & 1u);   // round-to-nearest-even
    return (unsigned short)(u >> 16);
}
__device__ __forceinline__ float bf16_to_f32(unsigned short h) {
    return __uint_as_float(((unsigned int)h) << 16);
}
// packed f32->bf16 pair: lo16 = cvt(a), hi16 = cvt(b)
__device__ __forceinline__ unsigned int cvt_pk_bf16(float a, float b) {
    unsigned int r;
    asm("v_cvt_pk_bf16_f32 %0, %1, %2" : "=v"(r) : "v"(a), "v"(b));
    return r;
}
// async global->LDS, 16B per lane. LDS dest is wave-uniform base + lane*16.
__device__ __forceinline__ void async16(const unsigned short* g, unsigned short* l) {
    __builtin_amdgcn_global_load_lds(
        (const __attribute__((address_space(1))) unsigned int*)g,
        (__attribute__((address_space(3))) unsigned int*)l, 16, 0, 0);
}

// ---------------- fp32 -> bf16 cast ----------------
__global__ __launch_bounds__(256) void cast_f32_bf16(
    const float* __restrict__ in, unsigned short* __restrict__ out, int n4)
{
    int idx = blockIdx.x * 256 + threadIdx.x;
    if (idx >= n4) return;
    float4 v = ((const float4*)in)[idx];
    ushort4 o;
    o.x = f32_to_bf16(v.x); o.y = f32_to_bf16(v.y);
    o.z = f32_to_bf16(v.z); o.w = f32_to_bf16(v.w);
    ((ushort4*)out)[idx] = o;
}

// ---------------- bf16 gemm_bt: C = A[M,K] * B[N,K]^T ----------------
// 128x128 tile, BK=32, 256 thr / 4 waves, each wave 64x64 (4x4 MFMA tiles).
template<int WRITE_F32>
__global__ __launch_bounds__(256) void gemm_bt(
    const unsigned short* __restrict__ A,
    const unsigned short* __restrict__ B,
    void* __restrict__ Cout, int M, int N, int K)
{
    __shared__ __attribute__((aligned(16))) unsigned short sA[128*32];
    __shared__ __attribute__((aligned(16))) unsigned short sB[128*32];
    const int tid  = threadIdx.x;
    const int lane = tid & 63;
    const int wv   = tid >> 6;
    const int wm   = (wv >> 1) * 64;
    const int wn   = (wv & 1) * 64;
    const int quad = lane >> 4;
    const int lr   = lane & 15;
    const int m0 = blockIdx.y * 128;
    const int n0 = blockIdx.x * 128;

    f32x4 acc[4][4] = {};
    const int nkt = K >> 5;
    for (int kt = 0; kt < nkt; ++kt) {
        const int k0 = kt << 5;
        #pragma unroll
        for (int p = 0; p < 2; ++p) {
            int e  = (p*256 + tid) * 8;
            int r  = e >> 5;                  // tile-local row 0..127
            int cc = (e & 31) >> 3;           // phys chunk 0..3
            int gc = (cc ^ (r & 3)) * 8;      // swizzled logical col
            async16(&A[(size_t)(m0 + r)*K + k0 + gc], &sA[e]);
            async16(&B[(size_t)(n0 + r)*K + k0 + gc], &sB[e]);
        }
        __syncthreads();
        s16x8 af[4], bf[4];
        #pragma unroll
        for (int i = 0; i < 4; ++i) {
            int row = wm + i*16 + lr;
            af[i] = *(const s16x8*)&sA[row*32 + ((quad ^ (row & 3)) * 8)];
        }
        #pragma unroll
        for (int j = 0; j < 4; ++j) {
            int row = wn + j*16 + lr;
            bf[j] = *(const s16x8*)&sB[row*32 + ((quad ^ (row & 3)) * 8)];
        }
        #pragma unroll
        for (int i = 0; i < 4; ++i)
            #pragma unroll
            for (int j = 0; j < 4; ++j)
                acc[i][j] = __builtin_amdgcn_mfma_f32_16x16x32_bf16(af[i], bf[j], acc[i][j], 0, 0, 0);
        __syncthreads();
    }
    // C/D layout: col = lane&15, row = (lane>>4)*4 + reg  (m89/m91 verified)
    #pragma unroll
    for (int i = 0; i < 4; ++i) {
        #pragma unroll
        for (int j = 0; j < 4; ++j) {
            #pragma unroll
            for (int r = 0; r < 4; ++r) {
                size_t row = (size_t)(m0 + wm + i*16 + quad*4 + r);
                size_t col = (size_t)(n0 + wn + j*16 + lr);
                float v = acc[i][j][r];
                if (WRITE_F32) ((float*)Cout)[row*(size_t)N + col] = v;
                else ((unsigned short*)Cout)[row*(size_t)N + col] = f32_to_bf16(v);
            }
        }
    }
}

// ---------------- RoPE + [B*S, rowstride] -> [B,NH,S,128] ----------------
// oscale folds the attention scale (1/sqrt(128)*log2e) into Q; 1.0 for K.
template<int NHEADS>
__global__ __launch_bounds__(256) void rope_rearrange(
    const unsigned short* __restrict__ in, unsigned short* __restrict__ out,
    int rowstride, float oscale)
{
    constexpr int LH = (NHEADS == 32) ? 5 : 3;
    int idx = blockIdx.x * 256 + threadIdx.x;
    int i  = idx & 63;
    int hh = (idx >> 6) & (NHEADS - 1);
    int s  = (idx >> (6 + LH)) & 2047;
    int b  = idx >> (17 + LH);
    size_t inoff = (size_t)(b*2048 + s) * rowstride + hh*128 + i;
    float x1 = bf16_to_f32(in[inoff]);
    float x2 = bf16_to_f32(in[inoff + 64]);
    float freq = expf((float)i * -0.14391156831212787f);  // ln(10000)/64
    float ang  = (float)s * freq;
    float sn, cs;
    sincosf(ang, &sn, &cs);
    size_t outoff = ((size_t)(b*NHEADS + hh) * 2048 + s) * 128 + i;
    out[outoff]      = f32_to_bf16((x1*cs - x2*sn) * oscale);
    out[outoff + 64] = f32_to_bf16((x2*cs + x1*sn) * oscale);
}

// ---------------- V: KVlin[B*S, 2048] (cols 1024+) -> Vt [B,G,128,2048] ----
// LDS tile transpose: per block one (b,g) x 128-s tile.
// Output columns are PERMUTED within each 64-s block so that flash's packed
// K=32 PV fragment (kv = c*32 + sub16*16 + quad*4 + j0) is one contiguous
// 16B chunk: stored position p holds s-offset
//   g(p) = (p>>5)*32 + ((p>>2)&1)*16 + ((p>>3)&3)*4 + (p&3).
__global__ __launch_bounds__(256) void rearrange_vt(
    const unsigned short* __restrict__ in, unsigned short* __restrict__ out)
{
    __shared__ __attribute__((aligned(16))) unsigned short sS[128*136];
    const int tid = threadIdx.x;
    const int bg  = blockIdx.y;
    const int b   = bg >> 3, g = bg & 7;
    const int s0  = blockIdx.x * 128;
    // phase 1: load 128s x 128d coalesced, store to LDS [s][d] (pad 136)
    #pragma unroll
    for (int p = 0; p < 8; ++p) {
        int ce = p*256 + tid;          // chunk: s = ce>>4, dc = ce&15
        int s  = ce >> 4, dc = ce & 15;
        s16x8 v = *(const s16x8*)&in[(size_t)(b*2048 + s0 + s)*2048 + 1024 + g*128 + dc*8];
        *(s16x8*)&sS[s*136 + dc*8] = v;
    }
    __syncthreads();
    // phase 2: write out rows d, permuted-contiguous along s
    const int d    = tid & 127;
    const int half = tid >> 7;
    const size_t obase = ((size_t)(bg)*128 + d)*2048 + s0;
    #pragma unroll
    for (int i = 0; i < 8; ++i) {
        int sc   = half*8 + i;         // output 8-short chunk index 0..15
        int blk  = sc >> 3;            // which 64-block of the 128 tile
        int base = (sc & 7) * 8;       // position within 64-block
        s16x8 ov;
        #pragma unroll
        for (int j = 0; j < 8; ++j) {
            int p = base + j;
            int soff = blk*64 + ((p >> 5) << 5) + (((p >> 2) & 1) << 4)
                     + (((p >> 3) & 3) << 2) + (p & 3);
            ov[j] = (short)sS[soff*136 + d];
        }
        *(s16x8*)&out[obase + sc*8] = ov;
    }
}

// ---------------- flash attention v2 (S^T trick, 32 q-rows/wave) ----------
// grid (S/128, B*H), qbi reversed. WG = 128 q-rows, wave w owns 32.
// KV tiles of 64. K double-buffered (32KB), Vt single-buffered (16KB):
// 48KB LDS -> 3 blocks/CU. Vt latency hides under QK^T+softmax, enforced by
// counted s_waitcnt vmcnt(4) + raw s_barrier (next K tile stays in flight).
// QK^T computed TRANSPOSED (A=K, B=Q): S^T C-layout col=lane&15=q,
// row=quad*4+r=kv. PV packs TWO 16-kv sub-tiles into one dense K=32 MFMA:
// A-frag j=0..3 <- p[2c], j=4..7 <- p[2c+1]; the matching V fragment is one
// contiguous b128 thanks to rearrange_vt's column permutation.
// Q is pre-scaled by 1/sqrt(128)*log2e, so scores are already in exp2 units.
// Softmax: defer-max (THR=8 in exp2 units): skip O-rescale + alpha broadcast
// unless the per-row max grew by >8; l cross-lane reduction deferred to end.
__global__ __launch_bounds__(256, 3) void flash_attn(
    const unsigned short* __restrict__ Q,    // [B,H,S,128] (pre-scaled)
    const unsigned short* __restrict__ K,    // [B,G,S,128]
    const unsigned short* __restrict__ Vt,   // [B,G,128,S] (col-permuted)
    unsigned short* __restrict__ ctx)        // [B*S, H*128]
{
    __shared__ __attribute__((aligned(16))) unsigned short sK[2][64*128];  // 32KB
    __shared__ __attribute__((aligned(16))) unsigned short sVt[128*64];    // 16KB

    const int tid  = threadIdx.x;
    const int lane = tid & 63;
    const int w    = tid >> 6;
    const int quad = lane >> 4;
    const int lr   = lane & 15;
    const int qbi = 15 - blockIdx.x;         // heavy blocks first
    const int b  = blockIdx.y >> 5;
    const int h  = blockIdx.y & 31;
    const int g  = h >> 2;
    const int q0 = qbi * 128;
    const int qw0 = q0 + w * 32;             // wave's first q-row
    const int KT = 2*qbi + 2;                // kv tiles needed by this WG

    s16x8 qf[2][4];                          // B-frag: n=q=lane&15, k=d=quad*8+j
    #pragma unroll
    for (int qt = 0; qt < 2; ++qt) {
        const size_t qrow = ((size_t)(b*32 + h) * 2048 + qw0 + qt*16 + lr) * 128;
        #pragma unroll
        for (int kc = 0; kc < 4; ++kc)
            qf[qt][kc] = *(const s16x8*)&Q[qrow + kc*32 + quad*8];
    }
    const size_t kvbase = (size_t)(b*8 + g) * 2048 * 128;
    const size_t vtbase = (size_t)(b*8 + g) * 128 * 2048;

    auto stageK = [&](int kt, int bi) {
        const size_t kbase = kvbase + (size_t)kt*64*128;
        #pragma unroll
        for (int p = 0; p < 4; ++p) {                 // K: async, swizzled
            int e = (p*256 + tid) * 8;
            int r = e >> 7;
            int s = (e & 127) >> 3;
            int gsrc = (s ^ (r & 15)) * 8;
            async16(&K[kbase + (size_t)r*128 + gsrc], &sK[bi][e]);
        }
    };
    auto stageV = [&](int kt) {
        #pragma unroll
        for (int p = 0; p < 4; ++p) {                 // Vt: async, swizzled
            int ce = p*256 + tid;                     // d = ce>>3, c = ce&7
            int d  = ce >> 3;
            int c  = ce & 7;
            int gc = (c ^ (d & 7)) * 8;
            async16(&Vt[vtbase + (size_t)d*2048 + kt*64 + gc], &sVt[ce*8]);
        }
    };

    float m_[2] = {-1e30f, -1e30f};
    float l_[2] = {0.f, 0.f};                // per-quad partial; reduced at end
    f32x4 o[2][8] = {};

    stageK(0, 0);
    for (int kt = 0; kt < KT; ++kt) {
        const int buf = kt & 1;
        __syncthreads();                     // A: K(kt) landed; sVt free (WAR)
        stageV(kt);                          // issue Vt(kt) first (oldest 4)
        __builtin_amdgcn_sched_barrier(0);   // pin V-before-K issue order
        if (kt + 1 < KT) stageK(kt + 1, buf ^ 1);

        const bool act = (kt*64 <= qw0 + 31);     // wave has visible kv
        const bool v0  = (kt*64 <= qw0 + 15);     // qt=0 sub-tile visible
        U8 pa[2][2];
        if (act) {
            f32x4 sacc[2][4] = {};           // S^T tiles: [qt][ct]
            #pragma unroll
            for (int ct = 0; ct < 4; ++ct) {
                int row = ct*16 + lr;        // kv-local (A m-index)
                #pragma unroll
                for (int kc = 0; kc < 4; ++kc) {
                    s16x8 kf = *(const s16x8*)&sK[buf][row*128 + (((kc*4 + quad) ^ lr)*8)];
                    if (v0) sacc[0][ct] = __builtin_amdgcn_mfma_f32_16x16x32_bf16(kf, qf[0][kc], sacc[0][ct], 0, 0, 0);
                    sacc[1][ct] = __builtin_amdgcn_mfma_f32_16x16x32_bf16(kf, qf[1][kc], sacc[1][ct], 0, 0, 0);
                }
            }
            #pragma unroll
            for (int qt = 0; qt < 2; ++qt) {
                if (qt == 0 && !v0) continue;
                const int qbase = qw0 + qt*16;
                const bool anymask = (kt*64 + 63) > qbase;
                const int qg = qbase + lr;   // this lane's q-row
                float p[4][4];
                float vmax = -1e30f;
                #pragma unroll
                for (int ct = 0; ct < 4; ++ct)
                    #pragma unroll
                    for (int r = 0; r < 4; ++r) {
                        float sv = sacc[qt][ct][r];
                        if (anymask) {
                            int kv = kt*64 + ct*16 + quad*4 + r;
                            if (kv > qg) sv = -1e30f;
                        }
                        p[ct][r] = sv;
                        vmax = fmaxf(vmax, sv);
                    }
                vmax = fmaxf(vmax, __shfl_xor(vmax, 16));
                vmax = fmaxf(vmax, __shfl_xor(vmax, 32));
                float mcur;
                if (__any(vmax > m_[qt] + 8.f)) {     // rare: rescale needed
                    float mnew = fmaxf(m_[qt], vmax);
                    float alpha = exp2f(m_[qt] - mnew);
                    m_[qt] = mnew;
                    mcur = mnew;
                    l_[qt] *= alpha;
                    f32x4 av;                // alpha per O-row q=quad*4+r
                    #pragma unroll
                    for (int r = 0; r < 4; ++r)
                        av[r] = __shfl(alpha, quad*4 + r);
                    #pragma unroll
                    for (int t = 0; t < 8; ++t)
                        o[qt][t] = o[qt][t] * av;
                } else {
                    mcur = m_[qt];           // defer: P bounded by 2^8
                }
                float rs = 0.f;
                #pragma unroll
                for (int ct = 0; ct < 4; ++ct)
                    #pragma unroll
                    for (int r = 0; r < 4; ++r) {
                        float pv = exp2f(p[ct][r] - mcur);
                        p[ct][r] = pv;
                        rs += pv;
                    }
                l_[qt] += rs;                // quad-partial; reduced in epilogue
                // pack P -> dense K=32 A-frags (j=0..3 <- 2c, j=4..7 <- 2c+1)
                pa[qt][0].u[0] = cvt_pk_bf16(p[0][0], p[0][1]);
                pa[qt][0].u[1] = cvt_pk_bf16(p[0][2], p[0][3]);
                pa[qt][0].u[2] = cvt_pk_bf16(p[1][0], p[1][1]);
                pa[qt][0].u[3] = cvt_pk_bf16(p[1][2], p[1][3]);
                pa[qt][1].u[0] = cvt_pk_bf16(p[2][0], p[2][1]);
                pa[qt][1].u[1] = cvt_pk_bf16(p[2][2], p[2][3]);
                pa[qt][1].u[2] = cvt_pk_bf16(p[3][0], p[3][1]);
                pa[qt][1].u[3] = cvt_pk_bf16(p[3][2], p[3][3]);
            }
        }
        // B: Vt(kt) landed for ALL waves; K(kt+1) stays in flight across PV.
        if (kt + 1 < KT) asm volatile("s_waitcnt vmcnt(4)" ::: "memory");
        else             asm volatile("s_waitcnt vmcnt(0)" ::: "memory");
        __builtin_amdgcn_s_barrier();
        __builtin_amdgcn_sched_barrier(0);
        if (act) {
            const int dk = lr & 7;
            #pragma unroll
            for (int t = 0; t < 8; ++t) {    // O += P V (dense K=32)
                const int d = t*16 + lr;
                #pragma unroll
                for (int c = 0; c < 2; ++c) {
                    s16x8 v8 = *(const s16x8*)&sVt[d*64 + (((c*4 + quad) ^ dk)*8)];
                    if (v0) o[0][t] = __builtin_amdgcn_mfma_f32_16x16x32_bf16(pa[0][c].v, v8, o[0][t], 0, 0, 0);
                    o[1][t] = __builtin_amdgcn_mfma_f32_16x16x32_bf16(pa[1][c].v, v8, o[1][t], 0, 0, 0);
                }
            }
        }
    }
    #pragma unroll
    for (int qt = 0; qt < 2; ++qt) {
        float lt = l_[qt];
        lt += __shfl_xor(lt, 16);            // deferred cross-quad reduction
        lt += __shfl_xor(lt, 32);
        f32x4 lv;
        #pragma unroll
        for (int r = 0; r < 4; ++r)
            lv[r] = __shfl(lt, quad*4 + r);
        #pragma unroll
        for (int r = 0; r < 4; ++r) {
            float inv = 1.0f / lv[r];
            int q = q0 + w*32 + qt*16 + quad*4 + r;
            size_t obase = ((size_t)b*2048 + q) * 4096 + h*128;
            #pragma unroll
            for (int t = 0; t < 8; ++t)
                ctx[obase + t*16 + lr] = f32_to_bf16(o[qt][t][r] * inv);
        }
    }
}

extern "C" void kernel_launch(void* const* d_in, const int* in_sizes, int n_in,
                              void* d_out, int out_size, void* d_ws, size_t ws_size,
                              hipStream_t stream)
{
    const float* x  = (const float*)d_in[0];
    const float* Wq = (const float*)d_in[1];
    const float* Wk = (const float*)d_in[2];
    const float* Wv = (const float*)d_in[3];
    const float* Wo = (const float*)d_in[4];
    float* out = (float*)d_out;
    char* ws = (char*)d_ws;

    // workspace layout (184,549,376 B total)
    unsigned short* xb    = (unsigned short*)(ws);              // 33.5 MB
    unsigned short* Wqb   = (unsigned short*)(ws + 33554432);   // 33.5 MB
    unsigned short* Wkvb  = (unsigned short*)(ws + 67108864);   // 16.8 MB (K rows 0..1023, V rows 1024..2047)
    unsigned short* Wob   = (unsigned short*)(ws + 83886080);   // 33.5 MB
    unsigned short* Qlin  = (unsigned short*)(ws + 117440512);  // 33.5 MB
    unsigned short* KVlin = (unsigned short*)(ws + 150994944);  // 16.8 MB [B*S, 2048]
    unsigned short* Kr    = (unsigned short*)(ws + 167772160);  //  8.4 MB
    unsigned short* Vt    = (unsigned short*)(ws + 176160768);  //  8.4 MB [B,G,128,S]
    unsigned short* Qr    = xb;    // alias: xb dead after QKV GEMMs
    unsigned short* ctxb  = Qlin;  // alias: Qlin dead after rope

    cast_f32_bf16<<<16384, 256, 0, stream>>>(x,  xb,  4194304);
    cast_f32_bf16<<<16384, 256, 0, stream>>>(Wq, Wqb, 4194304);
    cast_f32_bf16<<<4096,  256, 0, stream>>>(Wk, Wkvb,           1048576);
    cast_f32_bf16<<<4096,  256, 0, stream>>>(Wv, Wkvb + 4194304, 1048576);
    cast_f32_bf16<<<16384, 256, 0, stream>>>(Wo, Wob, 4194304);

    gemm_bt<0><<<dim3(32, 32), 256, 0, stream>>>(xb, Wqb,  Qlin,  4096, 4096, 4096);
    gemm_bt<0><<<dim3(16, 32), 256, 0, stream>>>(xb, Wkvb, KVlin, 4096, 2048, 4096);

    // Q pre-scaled by 1/sqrt(128)*log2(e); K unscaled.
    rope_rearrange<32><<<32768, 256, 0, stream>>>(Qlin,  Qr, 4096, 0.12751646f);
    rope_rearrange<8><<<8192,   256, 0, stream>>>(KVlin, Kr, 2048, 1.0f);
    rearrange_vt<<<dim3(16, 16), 256, 0, stream>>>(KVlin, Vt);

    flash_attn<<<dim3(16, 64), 256, 0, stream>>>(Qr, Kr, Vt, ctxb);

    gemm_bt<1><<<dim3(32, 32), 256, 0, stream>>>(ctxb, Wob, out, 4096, 4096, 4096);
}

// Round 3
// 997.920 us; speedup vs baseline: 1.2619x; 1.2619x over previous
//
#include <hip/hip_runtime.h>

// Problem constants: B=2, S=2048, D_IN=D_OUT=4096, H=32, G=8, HD=128, GS=4
// All matmuls are C[M,N] = A[M,K] @ B[N,K]^T ("gemm_bt", K contiguous in both).

typedef float f32x4 __attribute__((ext_vector_type(4)));
typedef short s16x8 __attribute__((ext_vector_type(8)));

union U8 { s16x8 v; unsigned int u[4]; };

__device__ __forceinline__ unsigned short f32_to_bf16(float f) {
    unsigned int u = __float_as_uint(f);
    u += 0x7fffu + ((u >> 16) & 1u);   // round-to-nearest-even
    return (unsigned short)(u >> 16);
}
__device__ __forceinline__ float bf16_to_f32(unsigned short h) {
    return __uint_as_float(((unsigned int)h) << 16);
}
// packed f32->bf16 pair: lo16 = cvt(a), hi16 = cvt(b)
__device__ __forceinline__ unsigned int cvt_pk_bf16(float a, float b) {
    unsigned int r;
    asm("v_cvt_pk_bf16_f32 %0, %1, %2" : "=v"(r) : "v"(a), "v"(b));
    return r;
}
// async global->LDS, 16B per lane. LDS dest is wave-uniform base + lane*16.
__device__ __forceinline__ void async16(const unsigned short* g, unsigned short* l) {
    __builtin_amdgcn_global_load_lds(
        (const __attribute__((address_space(1))) unsigned int*)g,
        (__attribute__((address_space(3))) unsigned int*)l, 16, 0, 0);
}

// ---------------- fp32 -> bf16 cast ----------------
__global__ __launch_bounds__(256) void cast_f32_bf16(
    const float* __restrict__ in, unsigned short* __restrict__ out, int n4)
{
    int idx = blockIdx.x * 256 + threadIdx.x;
    if (idx >= n4) return;
    float4 v = ((const float4*)in)[idx];
    ushort4 o;
    o.x = f32_to_bf16(v.x); o.y = f32_to_bf16(v.y);
    o.z = f32_to_bf16(v.z); o.w = f32_to_bf16(v.w);
    ((ushort4*)out)[idx] = o;
}

// ---------------- bf16 gemm_bt: C = A[M,K] * B[N,K]^T ----------------
// 128x128 tile, BK=32, 256 thr / 4 waves, each wave 64x64 (4x4 MFMA tiles).
template<int WRITE_F32>
__global__ __launch_bounds__(256) void gemm_bt(
    const unsigned short* __restrict__ A,
    const unsigned short* __restrict__ B,
    void* __restrict__ Cout, int M, int N, int K)
{
    __shared__ __attribute__((aligned(16))) unsigned short sA[128*32];
    __shared__ __attribute__((aligned(16))) unsigned short sB[128*32];
    const int tid  = threadIdx.x;
    const int lane = tid & 63;
    const int wv   = tid >> 6;
    const int wm   = (wv >> 1) * 64;
    const int wn   = (wv & 1) * 64;
    const int quad = lane >> 4;
    const int lr   = lane & 15;
    const int m0 = blockIdx.y * 128;
    const int n0 = blockIdx.x * 128;

    f32x4 acc[4][4] = {};
    const int nkt = K >> 5;
    for (int kt = 0; kt < nkt; ++kt) {
        const int k0 = kt << 5;
        #pragma unroll
        for (int p = 0; p < 2; ++p) {
            int e  = (p*256 + tid) * 8;
            int r  = e >> 5;                  // tile-local row 0..127
            int cc = (e & 31) >> 3;           // phys chunk 0..3
            int gc = (cc ^ (r & 3)) * 8;      // swizzled logical col
            async16(&A[(size_t)(m0 + r)*K + k0 + gc], &sA[e]);
            async16(&B[(size_t)(n0 + r)*K + k0 + gc], &sB[e]);
        }
        __syncthreads();
        s16x8 af[4], bf[4];
        #pragma unroll
        for (int i = 0; i < 4; ++i) {
            int row = wm + i*16 + lr;
            af[i] = *(const s16x8*)&sA[row*32 + ((quad ^ (row & 3)) * 8)];
        }
        #pragma unroll
        for (int j = 0; j < 4; ++j) {
            int row = wn + j*16 + lr;
            bf[j] = *(const s16x8*)&sB[row*32 + ((quad ^ (row & 3)) * 8)];
        }
        #pragma unroll
        for (int i = 0; i < 4; ++i)
            #pragma unroll
            for (int j = 0; j < 4; ++j)
                acc[i][j] = __builtin_amdgcn_mfma_f32_16x16x32_bf16(af[i], bf[j], acc[i][j], 0, 0, 0);
        __syncthreads();
    }
    // C/D layout: col = lane&15, row = (lane>>4)*4 + reg  (m89/m91 verified)
    #pragma unroll
    for (int i = 0; i < 4; ++i) {
        #pragma unroll
        for (int j = 0; j < 4; ++j) {
            #pragma unroll
            for (int r = 0; r < 4; ++r) {
                size_t row = (size_t)(m0 + wm + i*16 + quad*4 + r);
                size_t col = (size_t)(n0 + wn + j*16 + lr);
                float v = acc[i][j][r];
                if (WRITE_F32) ((float*)Cout)[row*(size_t)N + col] = v;
                else ((unsigned short*)Cout)[row*(size_t)N + col] = f32_to_bf16(v);
            }
        }
    }
}

// ---------------- RoPE + [B*S, rowstride] -> [B,NH,S,128] ----------------
// oscale folds the attention scale (1/sqrt(128)*log2e) into Q; 1.0 for K.
template<int NHEADS>
__global__ __launch_bounds__(256) void rope_rearrange(
    const unsigned short* __restrict__ in, unsigned short* __restrict__ out,
    int rowstride, float oscale)
{
    constexpr int LH = (NHEADS == 32) ? 5 : 3;
    int idx = blockIdx.x * 256 + threadIdx.x;
    int i  = idx & 63;
    int hh = (idx >> 6) & (NHEADS - 1);
    int s  = (idx >> (6 + LH)) & 2047;
    int b  = idx >> (17 + LH);
    size_t inoff = (size_t)(b*2048 + s) * rowstride + hh*128 + i;
    float x1 = bf16_to_f32(in[inoff]);
    float x2 = bf16_to_f32(in[inoff + 64]);
    float freq = expf((float)i * -0.14391156831212787f);  // ln(10000)/64
    float ang  = (float)s * freq;
    float sn, cs;
    sincosf(ang, &sn, &cs);
    size_t outoff = ((size_t)(b*NHEADS + hh) * 2048 + s) * 128 + i;
    out[outoff]      = f32_to_bf16((x1*cs - x2*sn) * oscale);
    out[outoff + 64] = f32_to_bf16((x2*cs + x1*sn) * oscale);
}

// ---------------- V: KVlin[B*S, 2048] (cols 1024+) -> Vt [B,G,128,2048] ----
// LDS tile transpose: per block one (b,g) x 128-s tile.
// Output columns are PERMUTED within each 64-s block so that flash's packed
// K=32 PV fragment (kv = c*32 + sub16*16 + quad*4 + j0) is one contiguous
// 16B chunk: stored position p holds s-offset
//   g(p) = (p>>5)*32 + ((p>>2)&1)*16 + ((p>>3)&3)*4 + (p&3).
__global__ __launch_bounds__(256) void rearrange_vt(
    const unsigned short* __restrict__ in, unsigned short* __restrict__ out)
{
    __shared__ __attribute__((aligned(16))) unsigned short sS[128*136];
    const int tid = threadIdx.x;
    const int bg  = blockIdx.y;
    const int b   = bg >> 3, g = bg & 7;
    const int s0  = blockIdx.x * 128;
    // phase 1: load 128s x 128d coalesced, store to LDS [s][d] (pad 136)
    #pragma unroll
    for (int p = 0; p < 8; ++p) {
        int ce = p*256 + tid;          // chunk: s = ce>>4, dc = ce&15
        int s  = ce >> 4, dc = ce & 15;
        s16x8 v = *(const s16x8*)&in[(size_t)(b*2048 + s0 + s)*2048 + 1024 + g*128 + dc*8];
        *(s16x8*)&sS[s*136 + dc*8] = v;
    }
    __syncthreads();
    // phase 2: write out rows d, permuted-contiguous along s
    const int d    = tid & 127;
    const int half = tid >> 7;
    const size_t obase = ((size_t)(bg)*128 + d)*2048 + s0;
    #pragma unroll
    for (int i = 0; i < 8; ++i) {
        int sc   = half*8 + i;         // output 8-short chunk index 0..15
        int blk  = sc >> 3;            // which 64-block of the 128 tile
        int base = (sc & 7) * 8;       // position within 64-block
        s16x8 ov;
        #pragma unroll
        for (int j = 0; j < 8; ++j) {
            int p = base + j;
            int soff = blk*64 + ((p >> 5) << 5) + (((p >> 2) & 1) << 4)
                     + (((p >> 3) & 3) << 2) + (p & 3);
            ov[j] = (short)sS[soff*136 + d];
        }
        *(s16x8*)&out[obase + sc*8] = ov;
    }
}

// ---------------- flash attention v2 (S^T trick, 32 q-rows/wave) ----------
// grid (S/128, B*H), qbi reversed. WG = 128 q-rows, wave w owns 32.
// KV tiles of 64. K AND Vt double-buffered (64KB LDS, 2 blocks/CU):
// proven round-0 schedule — ONE __syncthreads per tile, tile kt+1's 8 loads
// issued right after it, a full iteration (QK+softmax+PV) to land.
// launch_bounds(256,2): unified VGPR+AGPR cap 256 — no spill (the (256,3)
// variant spilled ~50 regs -> +39MB scratch writes, 1.6x slower).
// QK^T computed TRANSPOSED (A=K, B=Q): S^T C-layout col=lane&15=q,
// row=quad*4+r=kv. PV packs TWO 16-kv sub-tiles into one dense K=32 MFMA:
// A-frag j=0..3 <- p[2c], j=4..7 <- p[2c+1]; the matching V fragment is one
// contiguous b128 thanks to rearrange_vt's column permutation (verified r2).
// Q pre-scaled by 1/sqrt(128)*log2e. Defer-max (THR=8): skip O-rescale
// unless per-row max grew >8; l cross-lane reduction deferred to epilogue.
__global__ __launch_bounds__(256, 2) void flash_attn(
    const unsigned short* __restrict__ Q,    // [B,H,S,128] (pre-scaled)
    const unsigned short* __restrict__ K,    // [B,G,S,128]
    const unsigned short* __restrict__ Vt,   // [B,G,128,S] (col-permuted)
    unsigned short* __restrict__ ctx)        // [B*S, H*128]
{
    __shared__ __attribute__((aligned(16))) unsigned short sK[2][64*128];   // 2x16KB
    __shared__ __attribute__((aligned(16))) unsigned short sVt[2][128*64];  // 2x16KB

    const int tid  = threadIdx.x;
    const int lane = tid & 63;
    const int w    = tid >> 6;
    const int quad = lane >> 4;
    const int lr   = lane & 15;
    const int qbi = 15 - blockIdx.x;         // heavy blocks first
    const int b  = blockIdx.y >> 5;
    const int h  = blockIdx.y & 31;
    const int g  = h >> 2;
    const int q0 = qbi * 128;
    const int qw0 = q0 + w * 32;             // wave's first q-row
    const int KT = 2*qbi + 2;                // kv tiles needed by this WG

    s16x8 qf[2][4];                          // B-frag: n=q=lane&15, k=d=quad*8+j
    #pragma unroll
    for (int qt = 0; qt < 2; ++qt) {
        const size_t qrow = ((size_t)(b*32 + h) * 2048 + qw0 + qt*16 + lr) * 128;
        #pragma unroll
        for (int kc = 0; kc < 4; ++kc)
            qf[qt][kc] = *(const s16x8*)&Q[qrow + kc*32 + quad*8];
    }
    const size_t kvbase = (size_t)(b*8 + g) * 2048 * 128;
    const size_t vtbase = (size_t)(b*8 + g) * 128 * 2048;

    auto stage = [&](int kt, int bi) {
        const size_t kbase = kvbase + (size_t)kt*64*128;
        #pragma unroll
        for (int p = 0; p < 4; ++p) {                 // K: async, swizzled
            int e = (p*256 + tid) * 8;
            int r = e >> 7;
            int s = (e & 127) >> 3;
            int gsrc = (s ^ (r & 15)) * 8;
            async16(&K[kbase + (size_t)r*128 + gsrc], &sK[bi][e]);
        }
        #pragma unroll
        for (int p = 0; p < 4; ++p) {                 // Vt: async, swizzled
            int ce = p*256 + tid;                     // d = ce>>3, c = ce&7
            int d  = ce >> 3;
            int c  = ce & 7;
            int gc = (c ^ (d & 7)) * 8;
            async16(&Vt[vtbase + (size_t)d*2048 + kt*64 + gc], &sVt[bi][ce*8]);
        }
    };

    float m_[2] = {-1e30f, -1e30f};
    float l_[2] = {0.f, 0.f};                // per-quad partial; reduced at end
    f32x4 o[2][8] = {};

    stage(0, 0);
    int buf = 0;
    for (int kt = 0; kt < KT; ++kt) {
        __syncthreads();                     // drains vmcnt: tile kt landed
        if (kt + 1 < KT) stage(kt + 1, buf ^ 1);

        const bool act = (kt*64 <= qw0 + 31);     // wave has visible kv
        const bool v0  = (kt*64 <= qw0 + 15);     // qt=0 sub-tile visible
        if (act) {
            f32x4 sacc[2][4] = {};           // S^T tiles: [qt][ct]
            __builtin_amdgcn_s_setprio(1);
            #pragma unroll
            for (int ct = 0; ct < 4; ++ct) {
                int row = ct*16 + lr;        // kv-local (A m-index)
                #pragma unroll
                for (int kc = 0; kc < 4; ++kc) {
                    s16x8 kf = *(const s16x8*)&sK[buf][row*128 + (((kc*4 + quad) ^ lr)*8)];
                    if (v0) sacc[0][ct] = __builtin_amdgcn_mfma_f32_16x16x32_bf16(kf, qf[0][kc], sacc[0][ct], 0, 0, 0);
                    sacc[1][ct] = __builtin_amdgcn_mfma_f32_16x16x32_bf16(kf, qf[1][kc], sacc[1][ct], 0, 0, 0);
                }
            }
            __builtin_amdgcn_s_setprio(0);
            U8 pa[2][2];
            #pragma unroll
            for (int qt = 0; qt < 2; ++qt) {
                if (qt == 0 && !v0) continue;
                const int qbase = qw0 + qt*16;
                const bool anymask = (kt*64 + 63) > qbase;
                const int qg = qbase + lr;   // this lane's q-row
                float p[4][4];
                float vmax = -1e30f;
                #pragma unroll
                for (int ct = 0; ct < 4; ++ct)
                    #pragma unroll
                    for (int r = 0; r < 4; ++r) {
                        float sv = sacc[qt][ct][r];
                        if (anymask) {
                            int kv = kt*64 + ct*16 + quad*4 + r;
                            if (kv > qg) sv = -1e30f;
                        }
                        p[ct][r] = sv;
                        vmax = fmaxf(vmax, sv);
                    }
                vmax = fmaxf(vmax, __shfl_xor(vmax, 16));
                vmax = fmaxf(vmax, __shfl_xor(vmax, 32));
                float mcur;
                if (__any(vmax > m_[qt] + 8.f)) {     // rare: rescale needed
                    float mnew = fmaxf(m_[qt], vmax);
                    float alpha = exp2f(m_[qt] - mnew);
                    m_[qt] = mnew;
                    mcur = mnew;
                    l_[qt] *= alpha;
                    f32x4 av;                // alpha per O-row q=quad*4+r
                    #pragma unroll
                    for (int r = 0; r < 4; ++r)
                        av[r] = __shfl(alpha, quad*4 + r);
                    #pragma unroll
                    for (int t = 0; t < 8; ++t)
                        o[qt][t] = o[qt][t] * av;
                } else {
                    mcur = m_[qt];           // defer: P bounded by 2^8
                }
                float rs = 0.f;
                #pragma unroll
                for (int ct = 0; ct < 4; ++ct)
                    #pragma unroll
                    for (int r = 0; r < 4; ++r) {
                        float pv = exp2f(p[ct][r] - mcur);
                        p[ct][r] = pv;
                        rs += pv;
                    }
                l_[qt] += rs;                // quad-partial; reduced in epilogue
                // pack P -> dense K=32 A-frags (j=0..3 <- 2c, j=4..7 <- 2c+1)
                pa[qt][0].u[0] = cvt_pk_bf16(p[0][0], p[0][1]);
                pa[qt][0].u[1] = cvt_pk_bf16(p[0][2], p[0][3]);
                pa[qt][0].u[2] = cvt_pk_bf16(p[1][0], p[1][1]);
                pa[qt][0].u[3] = cvt_pk_bf16(p[1][2], p[1][3]);
                pa[qt][1].u[0] = cvt_pk_bf16(p[2][0], p[2][1]);
                pa[qt][1].u[1] = cvt_pk_bf16(p[2][2], p[2][3]);
                pa[qt][1].u[2] = cvt_pk_bf16(p[3][0], p[3][1]);
                pa[qt][1].u[3] = cvt_pk_bf16(p[3][2], p[3][3]);
            }
            const int dk = lr & 7;
            __builtin_amdgcn_s_setprio(1);
            #pragma unroll
            for (int t = 0; t < 8; ++t) {    // O += P V (dense K=32)
                const int d = t*16 + lr;
                #pragma unroll
                for (int c = 0; c < 2; ++c) {
                    s16x8 v8 = *(const s16x8*)&sVt[buf][d*64 + (((c*4 + quad) ^ dk)*8)];
                    if (v0) o[0][t] = __builtin_amdgcn_mfma_f32_16x16x32_bf16(pa[0][c].v, v8, o[0][t], 0, 0, 0);
                    o[1][t] = __builtin_amdgcn_mfma_f32_16x16x32_bf16(pa[1][c].v, v8, o[1][t], 0, 0, 0);
                }
            }
            __builtin_amdgcn_s_setprio(0);
        }
        buf ^= 1;
    }
    #pragma unroll
    for (int qt = 0; qt < 2; ++qt) {
        float lt = l_[qt];
        lt += __shfl_xor(lt, 16);            // deferred cross-quad reduction
        lt += __shfl_xor(lt, 32);
        f32x4 lv;
        #pragma unroll
        for (int r = 0; r < 4; ++r)
            lv[r] = __shfl(lt, quad*4 + r);
        #pragma unroll
        for (int r = 0; r < 4; ++r) {
            float inv = 1.0f / lv[r];
            int q = q0 + w*32 + qt*16 + quad*4 + r;
            size_t obase = ((size_t)b*2048 + q) * 4096 + h*128;
            #pragma unroll
            for (int t = 0; t < 8; ++t)
                ctx[obase + t*16 + lr] = f32_to_bf16(o[qt][t][r] * inv);
        }
    }
}

extern "C" void kernel_launch(void* const* d_in, const int* in_sizes, int n_in,
                              void* d_out, int out_size, void* d_ws, size_t ws_size,
                              hipStream_t stream)
{
    const float* x  = (const float*)d_in[0];
    const float* Wq = (const float*)d_in[1];
    const float* Wk = (const float*)d_in[2];
    const float* Wv = (const float*)d_in[3];
    const float* Wo = (const float*)d_in[4];
    float* out = (float*)d_out;
    char* ws = (char*)d_ws;

    // workspace layout (184,549,376 B total)
    unsigned short* xb    = (unsigned short*)(ws);              // 33.5 MB
    unsigned short* Wqb   = (unsigned short*)(ws + 33554432);   // 33.5 MB
    unsigned short* Wkvb  = (unsigned short*)(ws + 67108864);   // 16.8 MB (K rows 0..1023, V rows 1024..2047)
    unsigned short* Wob   = (unsigned short*)(ws + 83886080);   // 33.5 MB
    unsigned short* Qlin  = (unsigned short*)(ws + 117440512);  // 33.5 MB
    unsigned short* KVlin = (unsigned short*)(ws + 150994944);  // 16.8 MB [B*S, 2048]
    unsigned short* Kr    = (unsigned short*)(ws + 167772160);  //  8.4 MB
    unsigned short* Vt    = (unsigned short*)(ws + 176160768);  //  8.4 MB [B,G,128,S]
    unsigned short* Qr    = xb;    // alias: xb dead after QKV GEMMs
    unsigned short* ctxb  = Qlin;  // alias: Qlin dead after rope

    cast_f32_bf16<<<16384, 256, 0, stream>>>(x,  xb,  4194304);
    cast_f32_bf16<<<16384, 256, 0, stream>>>(Wq, Wqb, 4194304);
    cast_f32_bf16<<<4096,  256, 0, stream>>>(Wk, Wkvb,           1048576);
    cast_f32_bf16<<<4096,  256, 0, stream>>>(Wv, Wkvb + 4194304, 1048576);
    cast_f32_bf16<<<16384, 256, 0, stream>>>(Wo, Wob, 4194304);

    gemm_bt<0><<<dim3(32, 32), 256, 0, stream>>>(xb, Wqb,  Qlin,  4096, 4096, 4096);
    gemm_bt<0><<<dim3(16, 32), 256, 0, stream>>>(xb, Wkvb, KVlin, 4096, 2048, 4096);

    // Q pre-scaled by 1/sqrt(128)*log2(e); K unscaled.
    rope_rearrange<32><<<32768, 256, 0, stream>>>(Qlin,  Qr, 4096, 0.12751646f);
    rope_rearrange<8><<<8192,   256, 0, stream>>>(KVlin, Kr, 2048, 1.0f);
    rearrange_vt<<<dim3(16, 16), 256, 0, stream>>>(KVlin, Vt);

    flash_attn<<<dim3(16, 64), 256, 0, stream>>>(Qr, Kr, Vt, ctxb);

    gemm_bt<1><<<dim3(32, 32), 256, 0, stream>>>(ctxb, Wob, out, 4096, 4096, 4096);
}

// Round 4
// 914.550 us; speedup vs baseline: 1.3769x; 1.0912x over previous
//
#include <hip/hip_runtime.h>

// Problem constants: B=2, S=2048, D_IN=D_OUT=4096, H=32, G=8, HD=128, GS=4
// All matmuls are C[M,N] = A[M,K] @ B[N,K]^T ("gemm_bt", K contiguous in both).

typedef float f32x4 __attribute__((ext_vector_type(4)));
typedef short s16x8 __attribute__((ext_vector_type(8)));

union U8 { s16x8 v; unsigned int u[4]; };

__device__ __forceinline__ unsigned short f32_to_bf16(float f) {
    unsigned int u = __float_as_uint(f);
    u += 0x7fffu + ((u >> 16) & 1u);   // round-to-nearest-even
    return (unsigned short)(u >> 16);
}
__device__ __forceinline__ float bf16_to_f32(unsigned short h) {
    return __uint_as_float(((unsigned int)h) << 16);
}
// packed f32->bf16 pair: lo16 = cvt(a), hi16 = cvt(b)
__device__ __forceinline__ unsigned int cvt_pk_bf16(float a, float b) {
    unsigned int r;
    asm("v_cvt_pk_bf16_f32 %0, %1, %2" : "=v"(r) : "v"(a), "v"(b));
    return r;
}
// async global->LDS, 16B per lane. LDS dest is wave-uniform base + lane*16.
__device__ __forceinline__ void async16(const unsigned short* g, unsigned short* l) {
    __builtin_amdgcn_global_load_lds(
        (const __attribute__((address_space(1))) unsigned int*)g,
        (__attribute__((address_space(3))) unsigned int*)l, 16, 0, 0);
}

// ---------------- fp32 -> bf16 cast ----------------
__global__ __launch_bounds__(256) void cast_f32_bf16(
    const float* __restrict__ in, unsigned short* __restrict__ out, int n4)
{
    int idx = blockIdx.x * 256 + threadIdx.x;
    if (idx >= n4) return;
    float4 v = ((const float4*)in)[idx];
    ushort4 o;
    o.x = f32_to_bf16(v.x); o.y = f32_to_bf16(v.y);
    o.z = f32_to_bf16(v.z); o.w = f32_to_bf16(v.w);
    ((ushort4*)out)[idx] = o;
}

// ---------------- bf16 gemm_bt: C = A[M,K] * B[N,K]^T ----------------
// 128x128 tile, BK=32, 256 thr / 4 waves, each wave 64x64 (4x4 MFMA tiles).
// Double-buffered LDS (flash_attn-style): ONE __syncthreads per K-step,
// tile kt+1's loads issued right after it and given the whole compute phase
// to land (round-3 version drained vmcnt(0) immediately after issue: full
// HBM latency exposed per K-step -> 558 TF; dbuf structure = 839-890 TF).
// Chunk swizzle quad^((row>>1)&3): 16B slot = (row*4+phys) mod 8 covers all
// 8 slots per 8 rows -> 2-way (free). Old quad^(row&3) was 4-way (1.678e7
// SQ_LDS_BANK_CONFLICT).
template<int WRITE_F32>
__global__ __launch_bounds__(256) void gemm_bt(
    const unsigned short* __restrict__ A,
    const unsigned short* __restrict__ B,
    void* __restrict__ Cout, int M, int N, int K)
{
    __shared__ __attribute__((aligned(16))) unsigned short sA[2][128*32];
    __shared__ __attribute__((aligned(16))) unsigned short sB[2][128*32];
    const int tid  = threadIdx.x;
    const int lane = tid & 63;
    const int wv   = tid >> 6;
    const int wm   = (wv >> 1) * 64;
    const int wn   = (wv & 1) * 64;
    const int quad = lane >> 4;
    const int lr   = lane & 15;
    const int m0 = blockIdx.y * 128;
    const int n0 = blockIdx.x * 128;

    auto stage = [&](int kt, int bi) {
        const int k0 = kt << 5;
        #pragma unroll
        for (int p = 0; p < 2; ++p) {
            int e  = (p*256 + tid) * 8;
            int r  = e >> 5;                  // tile-local row 0..127
            int cc = (e & 31) >> 3;           // phys chunk 0..3
            int gc = (cc ^ ((r >> 1) & 3)) * 8;  // swizzled logical col
            async16(&A[(size_t)(m0 + r)*K + k0 + gc], &sA[bi][e]);
            async16(&B[(size_t)(n0 + r)*K + k0 + gc], &sB[bi][e]);
        }
    };

    f32x4 acc[4][4] = {};
    const int nkt = K >> 5;
    stage(0, 0);
    for (int kt = 0; kt < nkt; ++kt) {
        const int buf = kt & 1;
        __syncthreads();                     // tile kt landed; buf^1 readers done
        if (kt + 1 < nkt) stage(kt + 1, buf ^ 1);
        s16x8 af[4], bf[4];
        #pragma unroll
        for (int i = 0; i < 4; ++i) {
            int row = wm + i*16 + lr;
            af[i] = *(const s16x8*)&sA[buf][row*32 + ((quad ^ ((row >> 1) & 3)) * 8)];
        }
        #pragma unroll
        for (int j = 0; j < 4; ++j) {
            int row = wn + j*16 + lr;
            bf[j] = *(const s16x8*)&sB[buf][row*32 + ((quad ^ ((row >> 1) & 3)) * 8)];
        }
        #pragma unroll
        for (int i = 0; i < 4; ++i)
            #pragma unroll
            for (int j = 0; j < 4; ++j)
                acc[i][j] = __builtin_amdgcn_mfma_f32_16x16x32_bf16(af[i], bf[j], acc[i][j], 0, 0, 0);
    }
    // C/D layout: col = lane&15, row = (lane>>4)*4 + reg  (m89/m91 verified)
    #pragma unroll
    for (int i = 0; i < 4; ++i) {
        #pragma unroll
        for (int j = 0; j < 4; ++j) {
            #pragma unroll
            for (int r = 0; r < 4; ++r) {
                size_t row = (size_t)(m0 + wm + i*16 + quad*4 + r);
                size_t col = (size_t)(n0 + wn + j*16 + lr);
                float v = acc[i][j][r];
                if (WRITE_F32) ((float*)Cout)[row*(size_t)N + col] = v;
                else ((unsigned short*)Cout)[row*(size_t)N + col] = f32_to_bf16(v);
            }
        }
    }
}

// ---------------- RoPE + [B*S, rowstride] -> [B,NH,S,128] ----------------
// oscale folds the attention scale (1/sqrt(128)*log2e) into Q; 1.0 for K.
template<int NHEADS>
__global__ __launch_bounds__(256) void rope_rearrange(
    const unsigned short* __restrict__ in, unsigned short* __restrict__ out,
    int rowstride, float oscale)
{
    constexpr int LH = (NHEADS == 32) ? 5 : 3;
    int idx = blockIdx.x * 256 + threadIdx.x;
    int i  = idx & 63;
    int hh = (idx >> 6) & (NHEADS - 1);
    int s  = (idx >> (6 + LH)) & 2047;
    int b  = idx >> (17 + LH);
    size_t inoff = (size_t)(b*2048 + s) * rowstride + hh*128 + i;
    float x1 = bf16_to_f32(in[inoff]);
    float x2 = bf16_to_f32(in[inoff + 64]);
    float freq = expf((float)i * -0.14391156831212787f);  // ln(10000)/64
    float ang  = (float)s * freq;
    float sn, cs;
    sincosf(ang, &sn, &cs);
    size_t outoff = ((size_t)(b*NHEADS + hh) * 2048 + s) * 128 + i;
    out[outoff]      = f32_to_bf16((x1*cs - x2*sn) * oscale);
    out[outoff + 64] = f32_to_bf16((x2*cs + x1*sn) * oscale);
}

// ---------------- V: KVlin[B*S, 2048] (cols 1024+) -> Vt [B,G,128,2048] ----
// LDS tile transpose: per block one (b,g) x 128-s tile.
// Output columns are PERMUTED within each 64-s block so that flash's packed
// K=32 PV fragment (kv = c*32 + sub16*16 + quad*4 + j0) is one contiguous
// 16B chunk: stored position p holds s-offset
//   g(p) = (p>>5)*32 + ((p>>2)&1)*16 + ((p>>3)&3)*4 + (p&3).
__global__ __launch_bounds__(256) void rearrange_vt(
    const unsigned short* __restrict__ in, unsigned short* __restrict__ out)
{
    __shared__ __attribute__((aligned(16))) unsigned short sS[128*136];
    const int tid = threadIdx.x;
    const int bg  = blockIdx.y;
    const int b   = bg >> 3, g = bg & 7;
    const int s0  = blockIdx.x * 128;
    // phase 1: load 128s x 128d coalesced, store to LDS [s][d] (pad 136)
    #pragma unroll
    for (int p = 0; p < 8; ++p) {
        int ce = p*256 + tid;          // chunk: s = ce>>4, dc = ce&15
        int s  = ce >> 4, dc = ce & 15;
        s16x8 v = *(const s16x8*)&in[(size_t)(b*2048 + s0 + s)*2048 + 1024 + g*128 + dc*8];
        *(s16x8*)&sS[s*136 + dc*8] = v;
    }
    __syncthreads();
    // phase 2: write out rows d, permuted-contiguous along s
    const int d    = tid & 127;
    const int half = tid >> 7;
    const size_t obase = ((size_t)(bg)*128 + d)*2048 + s0;
    #pragma unroll
    for (int i = 0; i < 8; ++i) {
        int sc   = half*8 + i;         // output 8-short chunk index 0..15
        int blk  = sc >> 3;            // which 64-block of the 128 tile
        int base = (sc & 7) * 8;       // position within 64-block
        s16x8 ov;
        #pragma unroll
        for (int j = 0; j < 8; ++j) {
            int p = base + j;
            int soff = blk*64 + ((p >> 5) << 5) + (((p >> 2) & 1) << 4)
                     + (((p >> 3) & 3) << 2) + (p & 3);
            ov[j] = (short)sS[soff*136 + d];
        }
        *(s16x8*)&out[obase + sc*8] = ov;
    }
}

// ---------------- flash attention v2 (S^T trick, 32 q-rows/wave) ----------
// grid (S/128, B*H), qbi reversed. WG = 128 q-rows, wave w owns 32.
// KV tiles of 64. K AND Vt double-buffered (64KB LDS, 2 blocks/CU):
// proven round-0 schedule — ONE __syncthreads per tile, tile kt+1's 8 loads
// issued right after it, a full iteration (QK+softmax+PV) to land.
// launch_bounds(256,2): unified VGPR+AGPR cap 256 — no spill (the (256,3)
// variant spilled ~50 regs -> +39MB scratch writes, 1.6x slower).
// QK^T computed TRANSPOSED (A=K, B=Q): S^T C-layout col=lane&15=q,
// row=quad*4+r=kv. PV packs TWO 16-kv sub-tiles into one dense K=32 MFMA:
// A-frag j=0..3 <- p[2c], j=4..7 <- p[2c+1]; the matching V fragment is one
// contiguous b128 thanks to rearrange_vt's column permutation (verified r2).
// Q pre-scaled by 1/sqrt(128)*log2e. Defer-max (THR=8): skip O-rescale
// unless per-row max grew >8; l cross-lane reduction deferred to epilogue.
__global__ __launch_bounds__(256, 2) void flash_attn(
    const unsigned short* __restrict__ Q,    // [B,H,S,128] (pre-scaled)
    const unsigned short* __restrict__ K,    // [B,G,S,128]
    const unsigned short* __restrict__ Vt,   // [B,G,128,S] (col-permuted)
    unsigned short* __restrict__ ctx)        // [B*S, H*128]
{
    __shared__ __attribute__((aligned(16))) unsigned short sK[2][64*128];   // 2x16KB
    __shared__ __attribute__((aligned(16))) unsigned short sVt[2][128*64];  // 2x16KB

    const int tid  = threadIdx.x;
    const int lane = tid & 63;
    const int w    = tid >> 6;
    const int quad = lane >> 4;
    const int lr   = lane & 15;
    const int qbi = 15 - blockIdx.x;         // heavy blocks first
    const int b  = blockIdx.y >> 5;
    const int h  = blockIdx.y & 31;
    const int g  = h >> 2;
    const int q0 = qbi * 128;
    const int qw0 = q0 + w * 32;             // wave's first q-row
    const int KT = 2*qbi + 2;                // kv tiles needed by this WG

    s16x8 qf[2][4];                          // B-frag: n=q=lane&15, k=d=quad*8+j
    #pragma unroll
    for (int qt = 0; qt < 2; ++qt) {
        const size_t qrow = ((size_t)(b*32 + h) * 2048 + qw0 + qt*16 + lr) * 128;
        #pragma unroll
        for (int kc = 0; kc < 4; ++kc)
            qf[qt][kc] = *(const s16x8*)&Q[qrow + kc*32 + quad*8];
    }
    const size_t kvbase = (size_t)(b*8 + g) * 2048 * 128;
    const size_t vtbase = (size_t)(b*8 + g) * 128 * 2048;

    auto stage = [&](int kt, int bi) {
        const size_t kbase = kvbase + (size_t)kt*64*128;
        #pragma unroll
        for (int p = 0; p < 4; ++p) {                 // K: async, swizzled
            int e = (p*256 + tid) * 8;
            int r = e >> 7;
            int s = (e & 127) >> 3;
            int gsrc = (s ^ (r & 15)) * 8;
            async16(&K[kbase + (size_t)r*128 + gsrc], &sK[bi][e]);
        }
        #pragma unroll
        for (int p = 0; p < 4; ++p) {                 // Vt: async, swizzled
            int ce = p*256 + tid;                     // d = ce>>3, c = ce&7
            int d  = ce >> 3;
            int c  = ce & 7;
            int gc = (c ^ (d & 7)) * 8;
            async16(&Vt[vtbase + (size_t)d*2048 + kt*64 + gc], &sVt[bi][ce*8]);
        }
    };

    float m_[2] = {-1e30f, -1e30f};
    float l_[2] = {0.f, 0.f};                // per-quad partial; reduced at end
    f32x4 o[2][8] = {};

    stage(0, 0);
    int buf = 0;
    for (int kt = 0; kt < KT; ++kt) {
        __syncthreads();                     // drains vmcnt: tile kt landed
        if (kt + 1 < KT) stage(kt + 1, buf ^ 1);

        const bool act = (kt*64 <= qw0 + 31);     // wave has visible kv
        const bool v0  = (kt*64 <= qw0 + 15);     // qt=0 sub-tile visible
        if (act) {
            f32x4 sacc[2][4] = {};           // S^T tiles: [qt][ct]
            __builtin_amdgcn_s_setprio(1);
            #pragma unroll
            for (int ct = 0; ct < 4; ++ct) {
                int row = ct*16 + lr;        // kv-local (A m-index)
                #pragma unroll
                for (int kc = 0; kc < 4; ++kc) {
                    s16x8 kf = *(const s16x8*)&sK[buf][row*128 + (((kc*4 + quad) ^ lr)*8)];
                    if (v0) sacc[0][ct] = __builtin_amdgcn_mfma_f32_16x16x32_bf16(kf, qf[0][kc], sacc[0][ct], 0, 0, 0);
                    sacc[1][ct] = __builtin_amdgcn_mfma_f32_16x16x32_bf16(kf, qf[1][kc], sacc[1][ct], 0, 0, 0);
                }
            }
            __builtin_amdgcn_s_setprio(0);
            U8 pa[2][2];
            #pragma unroll
            for (int qt = 0; qt < 2; ++qt) {
                if (qt == 0 && !v0) continue;
                const int qbase = qw0 + qt*16;
                const bool anymask = (kt*64 + 63) > qbase;
                const int qg = qbase + lr;   // this lane's q-row
                float p[4][4];
                float vmax = -1e30f;
                #pragma unroll
                for (int ct = 0; ct < 4; ++ct)
                    #pragma unroll
                    for (int r = 0; r < 4; ++r) {
                        float sv = sacc[qt][ct][r];
                        if (anymask) {
                            int kv = kt*64 + ct*16 + quad*4 + r;
                            if (kv > qg) sv = -1e30f;
                        }
                        p[ct][r] = sv;
                        vmax = fmaxf(vmax, sv);
                    }
                vmax = fmaxf(vmax, __shfl_xor(vmax, 16));
                vmax = fmaxf(vmax, __shfl_xor(vmax, 32));
                float mcur;
                if (__any(vmax > m_[qt] + 8.f)) {     // rare: rescale needed
                    float mnew = fmaxf(m_[qt], vmax);
                    float alpha = exp2f(m_[qt] - mnew);
                    m_[qt] = mnew;
                    mcur = mnew;
                    l_[qt] *= alpha;
                    f32x4 av;                // alpha per O-row q=quad*4+r
                    #pragma unroll
                    for (int r = 0; r < 4; ++r)
                        av[r] = __shfl(alpha, quad*4 + r);
                    #pragma unroll
                    for (int t = 0; t < 8; ++t)
                        o[qt][t] = o[qt][t] * av;
                } else {
                    mcur = m_[qt];           // defer: P bounded by 2^8
                }
                float rs = 0.f;
                #pragma unroll
                for (int ct = 0; ct < 4; ++ct)
                    #pragma unroll
                    for (int r = 0; r < 4; ++r) {
                        float pv = exp2f(p[ct][r] - mcur);
                        p[ct][r] = pv;
                        rs += pv;
                    }
                l_[qt] += rs;                // quad-partial; reduced in epilogue
                // pack P -> dense K=32 A-frags (j=0..3 <- 2c, j=4..7 <- 2c+1)
                pa[qt][0].u[0] = cvt_pk_bf16(p[0][0], p[0][1]);
                pa[qt][0].u[1] = cvt_pk_bf16(p[0][2], p[0][3]);
                pa[qt][0].u[2] = cvt_pk_bf16(p[1][0], p[1][1]);
                pa[qt][0].u[3] = cvt_pk_bf16(p[1][2], p[1][3]);
                pa[qt][1].u[0] = cvt_pk_bf16(p[2][0], p[2][1]);
                pa[qt][1].u[1] = cvt_pk_bf16(p[2][2], p[2][3]);
                pa[qt][1].u[2] = cvt_pk_bf16(p[3][0], p[3][1]);
                pa[qt][1].u[3] = cvt_pk_bf16(p[3][2], p[3][3]);
            }
            const int dk = lr & 7;
            __builtin_amdgcn_s_setprio(1);
            #pragma unroll
            for (int t = 0; t < 8; ++t) {    // O += P V (dense K=32)
                const int d = t*16 + lr;
                #pragma unroll
                for (int c = 0; c < 2; ++c) {
                    s16x8 v8 = *(const s16x8*)&sVt[buf][d*64 + (((c*4 + quad) ^ dk)*8)];
                    if (v0) o[0][t] = __builtin_amdgcn_mfma_f32_16x16x32_bf16(pa[0][c].v, v8, o[0][t], 0, 0, 0);
                    o[1][t] = __builtin_amdgcn_mfma_f32_16x16x32_bf16(pa[1][c].v, v8, o[1][t], 0, 0, 0);
                }
            }
            __builtin_amdgcn_s_setprio(0);
        }
        buf ^= 1;
    }
    #pragma unroll
    for (int qt = 0; qt < 2; ++qt) {
        float lt = l_[qt];
        lt += __shfl_xor(lt, 16);            // deferred cross-quad reduction
        lt += __shfl_xor(lt, 32);
        f32x4 lv;
        #pragma unroll
        for (int r = 0; r < 4; ++r)
            lv[r] = __shfl(lt, quad*4 + r);
        #pragma unroll
        for (int r = 0; r < 4; ++r) {
            float inv = 1.0f / lv[r];
            int q = q0 + w*32 + qt*16 + quad*4 + r;
            size_t obase = ((size_t)b*2048 + q) * 4096 + h*128;
            #pragma unroll
            for (int t = 0; t < 8; ++t)
                ctx[obase + t*16 + lr] = f32_to_bf16(o[qt][t][r] * inv);
        }
    }
}

extern "C" void kernel_launch(void* const* d_in, const int* in_sizes, int n_in,
                              void* d_out, int out_size, void* d_ws, size_t ws_size,
                              hipStream_t stream)
{
    const float* x  = (const float*)d_in[0];
    const float* Wq = (const float*)d_in[1];
    const float* Wk = (const float*)d_in[2];
    const float* Wv = (const float*)d_in[3];
    const float* Wo = (const float*)d_in[4];
    float* out = (float*)d_out;
    char* ws = (char*)d_ws;

    // workspace layout (184,549,376 B total)
    unsigned short* xb    = (unsigned short*)(ws);              // 33.5 MB
    unsigned short* Wqb   = (unsigned short*)(ws + 33554432);   // 33.5 MB
    unsigned short* Wkvb  = (unsigned short*)(ws + 67108864);   // 16.8 MB (K rows 0..1023, V rows 1024..2047)
    unsigned short* Wob   = (unsigned short*)(ws + 83886080);   // 33.5 MB
    unsigned short* Qlin  = (unsigned short*)(ws + 117440512);  // 33.5 MB
    unsigned short* KVlin = (unsigned short*)(ws + 150994944);  // 16.8 MB [B*S, 2048]
    unsigned short* Kr    = (unsigned short*)(ws + 167772160);  //  8.4 MB
    unsigned short* Vt    = (unsigned short*)(ws + 176160768);  //  8.4 MB [B,G,128,S]
    unsigned short* Qr    = xb;    // alias: xb dead after QKV GEMMs
    unsigned short* ctxb  = Qlin;  // alias: Qlin dead after rope

    cast_f32_bf16<<<16384, 256, 0, stream>>>(x,  xb,  4194304);
    cast_f32_bf16<<<16384, 256, 0, stream>>>(Wq, Wqb, 4194304);
    cast_f32_bf16<<<4096,  256, 0, stream>>>(Wk, Wkvb,           1048576);
    cast_f32_bf16<<<4096,  256, 0, stream>>>(Wv, Wkvb + 4194304, 1048576);
    cast_f32_bf16<<<16384, 256, 0, stream>>>(Wo, Wob, 4194304);

    gemm_bt<0><<<dim3(32, 32), 256, 0, stream>>>(xb, Wqb,  Qlin,  4096, 4096, 4096);
    gemm_bt<0><<<dim3(16, 32), 256, 0, stream>>>(xb, Wkvb, KVlin, 4096, 2048, 4096);

    // Q pre-scaled by 1/sqrt(128)*log2(e); K unscaled.
    rope_rearrange<32><<<32768, 256, 0, stream>>>(Qlin,  Qr, 4096, 0.12751646f);
    rope_rearrange<8><<<8192,   256, 0, stream>>>(KVlin, Kr, 2048, 1.0f);
    rearrange_vt<<<dim3(16, 16), 256, 0, stream>>>(KVlin, Vt);

    flash_attn<<<dim3(16, 64), 256, 0, stream>>>(Qr, Kr, Vt, ctxb);

    gemm_bt<1><<<dim3(32, 32), 256, 0, stream>>>(ctxb, Wob, out, 4096, 4096, 4096);
}

// Round 5
// 909.664 us; speedup vs baseline: 1.3843x; 1.0054x over previous
//
#include <hip/hip_runtime.h>

// Problem constants: B=2, S=2048, D_IN=D_OUT=4096, H=32, G=8, HD=128, GS=4
// All matmuls are C[M,N] = A[M,K] @ B[N,K]^T ("gemm_bt", K contiguous in both).

typedef float f32x4 __attribute__((ext_vector_type(4)));
typedef short s16x8 __attribute__((ext_vector_type(8)));

union U8 { s16x8 v; unsigned int u[4]; };

__device__ __forceinline__ unsigned short f32_to_bf16(float f) {
    unsigned int u = __float_as_uint(f);
    u += 0x7fffu + ((u >> 16) & 1u);   // round-to-nearest-even
    return (unsigned short)(u >> 16);
}
__device__ __forceinline__ float bf16_to_f32(unsigned short h) {
    return __uint_as_float(((unsigned int)h) << 16);
}
// packed f32->bf16 pair: lo16 = cvt(a), hi16 = cvt(b)
__device__ __forceinline__ unsigned int cvt_pk_bf16(float a, float b) {
    unsigned int r;
    asm("v_cvt_pk_bf16_f32 %0, %1, %2" : "=v"(r) : "v"(a), "v"(b));
    return r;
}
// async global->LDS, 16B per lane. LDS dest is wave-uniform base + lane*16.
__device__ __forceinline__ void async16(const unsigned short* g, unsigned short* l) {
    __builtin_amdgcn_global_load_lds(
        (const __attribute__((address_space(1))) unsigned int*)g,
        (__attribute__((address_space(3))) unsigned int*)l, 16, 0, 0);
}

// ---------------- fp32 -> bf16 cast ----------------
__global__ __launch_bounds__(256) void cast_f32_bf16(
    const float* __restrict__ in, unsigned short* __restrict__ out, int n4)
{
    int idx = blockIdx.x * 256 + threadIdx.x;
    if (idx >= n4) return;
    float4 v = ((const float4*)in)[idx];
    ushort4 o;
    o.x = f32_to_bf16(v.x); o.y = f32_to_bf16(v.y);
    o.z = f32_to_bf16(v.z); o.w = f32_to_bf16(v.w);
    ((ushort4*)out)[idx] = o;
}

// ---------------- bf16 gemm_bt: C = A[M,K] * B[N,K]^T ----------------
// 128x128 tile, BK=32, 256 thr / 4 waves, each wave 64x64 (4x4 MFMA tiles).
// Double-buffered LDS (flash_attn-style): ONE __syncthreads per K-step,
// tile kt+1's loads issued right after it and given the whole compute phase
// to land (round-3 version drained vmcnt(0) immediately after issue: full
// HBM latency exposed per K-step -> 558 TF; dbuf structure = 839-890 TF).
// Chunk swizzle quad^((row>>1)&3): 16B slot = (row*4+phys) mod 8 covers all
// 8 slots per 8 rows -> 2-way (free). Old quad^(row&3) was 4-way (1.678e7
// SQ_LDS_BANK_CONFLICT).
template<int WRITE_F32>
__global__ __launch_bounds__(256) void gemm_bt(
    const unsigned short* __restrict__ A,
    const unsigned short* __restrict__ B,
    void* __restrict__ Cout, int M, int N, int K)
{
    __shared__ __attribute__((aligned(16))) unsigned short sA[2][128*32];
    __shared__ __attribute__((aligned(16))) unsigned short sB[2][128*32];
    const int tid  = threadIdx.x;
    const int lane = tid & 63;
    const int wv   = tid >> 6;
    const int wm   = (wv >> 1) * 64;
    const int wn   = (wv & 1) * 64;
    const int quad = lane >> 4;
    const int lr   = lane & 15;
    const int m0 = blockIdx.y * 128;
    const int n0 = blockIdx.x * 128;

    auto stage = [&](int kt, int bi) {
        const int k0 = kt << 5;
        #pragma unroll
        for (int p = 0; p < 2; ++p) {
            int e  = (p*256 + tid) * 8;
            int r  = e >> 5;                  // tile-local row 0..127
            int cc = (e & 31) >> 3;           // phys chunk 0..3
            int gc = (cc ^ ((r >> 1) & 3)) * 8;  // swizzled logical col
            async16(&A[(size_t)(m0 + r)*K + k0 + gc], &sA[bi][e]);
            async16(&B[(size_t)(n0 + r)*K + k0 + gc], &sB[bi][e]);
        }
    };

    f32x4 acc[4][4] = {};
    const int nkt = K >> 5;
    stage(0, 0);
    for (int kt = 0; kt < nkt; ++kt) {
        const int buf = kt & 1;
        __syncthreads();                     // tile kt landed; buf^1 readers done
        if (kt + 1 < nkt) stage(kt + 1, buf ^ 1);
        s16x8 af[4], bf[4];
        #pragma unroll
        for (int i = 0; i < 4; ++i) {
            int row = wm + i*16 + lr;
            af[i] = *(const s16x8*)&sA[buf][row*32 + ((quad ^ ((row >> 1) & 3)) * 8)];
        }
        #pragma unroll
        for (int j = 0; j < 4; ++j) {
            int row = wn + j*16 + lr;
            bf[j] = *(const s16x8*)&sB[buf][row*32 + ((quad ^ ((row >> 1) & 3)) * 8)];
        }
        #pragma unroll
        for (int i = 0; i < 4; ++i)
            #pragma unroll
            for (int j = 0; j < 4; ++j)
                acc[i][j] = __builtin_amdgcn_mfma_f32_16x16x32_bf16(af[i], bf[j], acc[i][j], 0, 0, 0);
    }
    // C/D layout: col = lane&15, row = (lane>>4)*4 + reg  (m89/m91 verified)
    #pragma unroll
    for (int i = 0; i < 4; ++i) {
        #pragma unroll
        for (int j = 0; j < 4; ++j) {
            #pragma unroll
            for (int r = 0; r < 4; ++r) {
                size_t row = (size_t)(m0 + wm + i*16 + quad*4 + r);
                size_t col = (size_t)(n0 + wn + j*16 + lr);
                float v = acc[i][j][r];
                if (WRITE_F32) ((float*)Cout)[row*(size_t)N + col] = v;
                else ((unsigned short*)Cout)[row*(size_t)N + col] = f32_to_bf16(v);
            }
        }
    }
}

// ---------------- RoPE + [B*S, rowstride] -> [B,NH,S,128] ----------------
// oscale folds the attention scale (1/sqrt(128)*log2e) into Q; 1.0 for K.
template<int NHEADS>
__global__ __launch_bounds__(256) void rope_rearrange(
    const unsigned short* __restrict__ in, unsigned short* __restrict__ out,
    int rowstride, float oscale)
{
    constexpr int LH = (NHEADS == 32) ? 5 : 3;
    int idx = blockIdx.x * 256 + threadIdx.x;
    int i  = idx & 63;
    int hh = (idx >> 6) & (NHEADS - 1);
    int s  = (idx >> (6 + LH)) & 2047;
    int b  = idx >> (17 + LH);
    size_t inoff = (size_t)(b*2048 + s) * rowstride + hh*128 + i;
    float x1 = bf16_to_f32(in[inoff]);
    float x2 = bf16_to_f32(in[inoff + 64]);
    float freq = expf((float)i * -0.14391156831212787f);  // ln(10000)/64
    float ang  = (float)s * freq;
    float sn, cs;
    sincosf(ang, &sn, &cs);
    size_t outoff = ((size_t)(b*NHEADS + hh) * 2048 + s) * 128 + i;
    out[outoff]      = f32_to_bf16((x1*cs - x2*sn) * oscale);
    out[outoff + 64] = f32_to_bf16((x2*cs + x1*sn) * oscale);
}

// ---------------- V: KVlin[B*S, 2048] (cols 1024+) -> Vt [B,G,128,2048] ----
// LDS tile transpose: per block one (b,g) x 128-s tile.
// Output columns are PERMUTED within each 64-s block so that flash's packed
// K=32 PV fragment (kv = c*32 + sub16*16 + quad*4 + j0) is one contiguous
// 16B chunk: stored position p holds s-offset
//   g(p) = (p>>5)*32 + ((p>>2)&1)*16 + ((p>>3)&3)*4 + (p&3).
__global__ __launch_bounds__(256) void rearrange_vt(
    const unsigned short* __restrict__ in, unsigned short* __restrict__ out)
{
    __shared__ __attribute__((aligned(16))) unsigned short sS[128*136];
    const int tid = threadIdx.x;
    const int bg  = blockIdx.y;
    const int b   = bg >> 3, g = bg & 7;
    const int s0  = blockIdx.x * 128;
    // phase 1: load 128s x 128d coalesced, store to LDS [s][d] (pad 136)
    #pragma unroll
    for (int p = 0; p < 8; ++p) {
        int ce = p*256 + tid;          // chunk: s = ce>>4, dc = ce&15
        int s  = ce >> 4, dc = ce & 15;
        s16x8 v = *(const s16x8*)&in[(size_t)(b*2048 + s0 + s)*2048 + 1024 + g*128 + dc*8];
        *(s16x8*)&sS[s*136 + dc*8] = v;
    }
    __syncthreads();
    // phase 2: write out rows d, permuted-contiguous along s
    const int d    = tid & 127;
    const int half = tid >> 7;
    const size_t obase = ((size_t)(bg)*128 + d)*2048 + s0;
    #pragma unroll
    for (int i = 0; i < 8; ++i) {
        int sc   = half*8 + i;         // output 8-short chunk index 0..15
        int blk  = sc >> 3;            // which 64-block of the 128 tile
        int base = (sc & 7) * 8;       // position within 64-block
        s16x8 ov;
        #pragma unroll
        for (int j = 0; j < 8; ++j) {
            int p = base + j;
            int soff = blk*64 + ((p >> 5) << 5) + (((p >> 2) & 1) << 4)
                     + (((p >> 3) & 3) << 2) + (p & 3);
            ov[j] = (short)sS[soff*136 + d];
        }
        *(s16x8*)&out[obase + sc*8] = ov;
    }
}

// ---------------- flash attention v2 (S^T trick, 32 q-rows/wave) ----------
// grid (S/128, B*H), qbi reversed. WG = 128 q-rows, wave w owns 32.
// KV tiles of 64. K double-buffered (32KB) + Vt SINGLE-buffered (16KB):
// 48KB LDS -> 3 blocks/CU (vs 2 at 64KB). launch_bounds stays (256,2) so
// the compiler is NOT reg-capped (round-2's (256,3) cap caused ~50-reg
// spill, +39MB scratch); at ~112 VGPR the HW fits 3 waves/SIMD on its own.
// Two-barrier schedule, per-wave counted vmcnt:
//   top:  vmcnt(0) [only K(kt)'s 4 loads outstanding] + barrier
//         -> K(kt) visible to all AND all waves done with PV(kt-1) (sVt WAR)
//   stage Vt(kt) then K(kt+1) (order pinned; vmcnt counting exact)
//   QK + softmax cover Vt's HBM latency
//   vmcnt(4) + barrier -> Vt landed everywhere; K(kt+1) stays in flight
//   PV
// QK^T computed TRANSPOSED (A=K, B=Q): S^T C-layout col=lane&15=q,
// row=quad*4+r=kv. PV packs TWO 16-kv sub-tiles into one dense K=32 MFMA:
// A-frag j=0..3 <- p[2c], j=4..7 <- p[2c+1]; the matching V fragment is one
// contiguous b128 thanks to rearrange_vt's column permutation (verified r2).
// Q pre-scaled by 1/sqrt(128)*log2e. Defer-max (THR=8): skip O-rescale
// unless per-row max grew >8; l cross-lane reduction deferred to epilogue.
__global__ __launch_bounds__(256, 2) void flash_attn(
    const unsigned short* __restrict__ Q,    // [B,H,S,128] (pre-scaled)
    const unsigned short* __restrict__ K,    // [B,G,S,128]
    const unsigned short* __restrict__ Vt,   // [B,G,128,S] (col-permuted)
    unsigned short* __restrict__ ctx)        // [B*S, H*128]
{
    __shared__ __attribute__((aligned(16))) unsigned short sK[2][64*128];  // 32KB
    __shared__ __attribute__((aligned(16))) unsigned short sVt[128*64];    // 16KB

    const int tid  = threadIdx.x;
    const int lane = tid & 63;
    const int w    = tid >> 6;
    const int quad = lane >> 4;
    const int lr   = lane & 15;
    const int qbi = 15 - blockIdx.x;         // heavy blocks first
    const int b  = blockIdx.y >> 5;
    const int h  = blockIdx.y & 31;
    const int g  = h >> 2;
    const int q0 = qbi * 128;
    const int qw0 = q0 + w * 32;             // wave's first q-row
    const int KT = 2*qbi + 2;                // kv tiles needed by this WG

    s16x8 qf[2][4];                          // B-frag: n=q=lane&15, k=d=quad*8+j
    #pragma unroll
    for (int qt = 0; qt < 2; ++qt) {
        const size_t qrow = ((size_t)(b*32 + h) * 2048 + qw0 + qt*16 + lr) * 128;
        #pragma unroll
        for (int kc = 0; kc < 4; ++kc)
            qf[qt][kc] = *(const s16x8*)&Q[qrow + kc*32 + quad*8];
    }
    const size_t kvbase = (size_t)(b*8 + g) * 2048 * 128;
    const size_t vtbase = (size_t)(b*8 + g) * 128 * 2048;

    auto stageK = [&](int kt, int bi) {
        const size_t kbase = kvbase + (size_t)kt*64*128;
        #pragma unroll
        for (int p = 0; p < 4; ++p) {                 // K: async, swizzled
            int e = (p*256 + tid) * 8;
            int r = e >> 7;
            int s = (e & 127) >> 3;
            int gsrc = (s ^ (r & 15)) * 8;
            async16(&K[kbase + (size_t)r*128 + gsrc], &sK[bi][e]);
        }
    };
    auto stageV = [&](int kt) {
        #pragma unroll
        for (int p = 0; p < 4; ++p) {                 // Vt: async, swizzled
            int ce = p*256 + tid;                     // d = ce>>3, c = ce&7
            int d  = ce >> 3;
            int c  = ce & 7;
            int gc = (c ^ (d & 7)) * 8;
            async16(&Vt[vtbase + (size_t)d*2048 + kt*64 + gc], &sVt[ce*8]);
        }
    };

    float m_[2] = {-1e30f, -1e30f};
    float l_[2] = {0.f, 0.f};                // per-quad partial; reduced at end
    f32x4 o[2][8] = {};

    stageK(0, 0);
    for (int kt = 0; kt < KT; ++kt) {
        const int buf = kt & 1;
        // K(kt) are this wave's only outstanding vmem ops here (plus, at
        // kt=0, the qf global loads -- draining those too is harmless).
        asm volatile("s_waitcnt vmcnt(0)" ::: "memory");
        __builtin_amdgcn_s_barrier();        // K(kt) in LDS; PV(kt-1) done (sVt WAR)
        __builtin_amdgcn_sched_barrier(0);
        stageV(kt);                          // issue Vt(kt) first (oldest 4)
        __builtin_amdgcn_sched_barrier(0);   // pin V-before-K issue order
        if (kt + 1 < KT) stageK(kt + 1, buf ^ 1);
        __builtin_amdgcn_sched_barrier(0);

        const bool act = (kt*64 <= qw0 + 31);     // wave has visible kv
        const bool v0  = (kt*64 <= qw0 + 15);     // qt=0 sub-tile visible
        U8 pa[2][2];
        if (act) {
            f32x4 sacc[2][4] = {};           // S^T tiles: [qt][ct]
            __builtin_amdgcn_s_setprio(1);
            #pragma unroll
            for (int ct = 0; ct < 4; ++ct) {
                int row = ct*16 + lr;        // kv-local (A m-index)
                #pragma unroll
                for (int kc = 0; kc < 4; ++kc) {
                    s16x8 kf = *(const s16x8*)&sK[buf][row*128 + (((kc*4 + quad) ^ lr)*8)];
                    if (v0) sacc[0][ct] = __builtin_amdgcn_mfma_f32_16x16x32_bf16(kf, qf[0][kc], sacc[0][ct], 0, 0, 0);
                    sacc[1][ct] = __builtin_amdgcn_mfma_f32_16x16x32_bf16(kf, qf[1][kc], sacc[1][ct], 0, 0, 0);
                }
            }
            __builtin_amdgcn_s_setprio(0);
            #pragma unroll
            for (int qt = 0; qt < 2; ++qt) {
                if (qt == 0 && !v0) continue;
                const int qbase = qw0 + qt*16;
                const bool anymask = (kt*64 + 63) > qbase;
                const int qg = qbase + lr;   // this lane's q-row
                float p[4][4];
                float vmax = -1e30f;
                #pragma unroll
                for (int ct = 0; ct < 4; ++ct)
                    #pragma unroll
                    for (int r = 0; r < 4; ++r) {
                        float sv = sacc[qt][ct][r];
                        if (anymask) {
                            int kv = kt*64 + ct*16 + quad*4 + r;
                            if (kv > qg) sv = -1e30f;
                        }
                        p[ct][r] = sv;
                        vmax = fmaxf(vmax, sv);
                    }
                vmax = fmaxf(vmax, __shfl_xor(vmax, 16));
                vmax = fmaxf(vmax, __shfl_xor(vmax, 32));
                float mcur;
                if (__any(vmax > m_[qt] + 8.f)) {     // rare: rescale needed
                    float mnew = fmaxf(m_[qt], vmax);
                    float alpha = exp2f(m_[qt] - mnew);
                    m_[qt] = mnew;
                    mcur = mnew;
                    l_[qt] *= alpha;
                    f32x4 av;                // alpha per O-row q=quad*4+r
                    #pragma unroll
                    for (int r = 0; r < 4; ++r)
                        av[r] = __shfl(alpha, quad*4 + r);
                    #pragma unroll
                    for (int t = 0; t < 8; ++t)
                        o[qt][t] = o[qt][t] * av;
                } else {
                    mcur = m_[qt];           // defer: P bounded by 2^8
                }
                float rs = 0.f;
                #pragma unroll
                for (int ct = 0; ct < 4; ++ct)
                    #pragma unroll
                    for (int r = 0; r < 4; ++r) {
                        float pv = exp2f(p[ct][r] - mcur);
                        p[ct][r] = pv;
                        rs += pv;
                    }
                l_[qt] += rs;                // quad-partial; reduced in epilogue
                // pack P -> dense K=32 A-frags (j=0..3 <- 2c, j=4..7 <- 2c+1)
                pa[qt][0].u[0] = cvt_pk_bf16(p[0][0], p[0][1]);
                pa[qt][0].u[1] = cvt_pk_bf16(p[0][2], p[0][3]);
                pa[qt][0].u[2] = cvt_pk_bf16(p[1][0], p[1][1]);
                pa[qt][0].u[3] = cvt_pk_bf16(p[1][2], p[1][3]);
                pa[qt][1].u[0] = cvt_pk_bf16(p[2][0], p[2][1]);
                pa[qt][1].u[1] = cvt_pk_bf16(p[2][2], p[2][3]);
                pa[qt][1].u[2] = cvt_pk_bf16(p[3][0], p[3][1]);
                pa[qt][1].u[3] = cvt_pk_bf16(p[3][2], p[3][3]);
            }
        }
        // Vt(kt) landed for ALL waves; K(kt+1)'s 4 loads stay in flight.
        if (kt + 1 < KT) asm volatile("s_waitcnt vmcnt(4)" ::: "memory");
        else             asm volatile("s_waitcnt vmcnt(0)" ::: "memory");
        __builtin_amdgcn_s_barrier();
        __builtin_amdgcn_sched_barrier(0);
        if (act) {
            const int dk = lr & 7;
            __builtin_amdgcn_s_setprio(1);
            #pragma unroll
            for (int t = 0; t < 8; ++t) {    // O += P V (dense K=32)
                const int d = t*16 + lr;
                #pragma unroll
                for (int c = 0; c < 2; ++c) {
                    s16x8 v8 = *(const s16x8*)&sVt[d*64 + (((c*4 + quad) ^ dk)*8)];
                    if (v0) o[0][t] = __builtin_amdgcn_mfma_f32_16x16x32_bf16(pa[0][c].v, v8, o[0][t], 0, 0, 0);
                    o[1][t] = __builtin_amdgcn_mfma_f32_16x16x32_bf16(pa[1][c].v, v8, o[1][t], 0, 0, 0);
                }
            }
            __builtin_amdgcn_s_setprio(0);
        }
    }
    #pragma unroll
    for (int qt = 0; qt < 2; ++qt) {
        float lt = l_[qt];
        lt += __shfl_xor(lt, 16);            // deferred cross-quad reduction
        lt += __shfl_xor(lt, 32);
        f32x4 lv;
        #pragma unroll
        for (int r = 0; r < 4; ++r)
            lv[r] = __shfl(lt, quad*4 + r);
        #pragma unroll
        for (int r = 0; r < 4; ++r) {
            float inv = 1.0f / lv[r];
            int q = q0 + w*32 + qt*16 + quad*4 + r;
            size_t obase = ((size_t)b*2048 + q) * 4096 + h*128;
            #pragma unroll
            for (int t = 0; t < 8; ++t)
                ctx[obase + t*16 + lr] = f32_to_bf16(o[qt][t][r] * inv);
        }
    }
}

extern "C" void kernel_launch(void* const* d_in, const int* in_sizes, int n_in,
                              void* d_out, int out_size, void* d_ws, size_t ws_size,
                              hipStream_t stream)
{
    const float* x  = (const float*)d_in[0];
    const float* Wq = (const float*)d_in[1];
    const float* Wk = (const float*)d_in[2];
    const float* Wv = (const float*)d_in[3];
    const float* Wo = (const float*)d_in[4];
    float* out = (float*)d_out;
    char* ws = (char*)d_ws;

    // workspace layout (184,549,376 B total)
    unsigned short* xb    = (unsigned short*)(ws);              // 33.5 MB
    unsigned short* Wqb   = (unsigned short*)(ws + 33554432);   // 33.5 MB
    unsigned short* Wkvb  = (unsigned short*)(ws + 67108864);   // 16.8 MB (K rows 0..1023, V rows 1024..2047)
    unsigned short* Wob   = (unsigned short*)(ws + 83886080);   // 33.5 MB
    unsigned short* Qlin  = (unsigned short*)(ws + 117440512);  // 33.5 MB
    unsigned short* KVlin = (unsigned short*)(ws + 150994944);  // 16.8 MB [B*S, 2048]
    unsigned short* Kr    = (unsigned short*)(ws + 167772160);  //  8.4 MB
    unsigned short* Vt    = (unsigned short*)(ws + 176160768);  //  8.4 MB [B,G,128,S]
    unsigned short* Qr    = xb;    // alias: xb dead after QKV GEMMs
    unsigned short* ctxb  = Qlin;  // alias: Qlin dead after rope

    cast_f32_bf16<<<16384, 256, 0, stream>>>(x,  xb,  4194304);
    cast_f32_bf16<<<16384, 256, 0, stream>>>(Wq, Wqb, 4194304);
    cast_f32_bf16<<<4096,  256, 0, stream>>>(Wk, Wkvb,           1048576);
    cast_f32_bf16<<<4096,  256, 0, stream>>>(Wv, Wkvb + 4194304, 1048576);
    cast_f32_bf16<<<16384, 256, 0, stream>>>(Wo, Wob, 4194304);

    gemm_bt<0><<<dim3(32, 32), 256, 0, stream>>>(xb, Wqb,  Qlin,  4096, 4096, 4096);
    gemm_bt<0><<<dim3(16, 32), 256, 0, stream>>>(xb, Wkvb, KVlin, 4096, 2048, 4096);

    // Q pre-scaled by 1/sqrt(128)*log2(e); K unscaled.
    rope_rearrange<32><<<32768, 256, 0, stream>>>(Qlin,  Qr, 4096, 0.12751646f);
    rope_rearrange<8><<<8192,   256, 0, stream>>>(KVlin, Kr, 2048, 1.0f);
    rearrange_vt<<<dim3(16, 16), 256, 0, stream>>>(KVlin, Vt);

    flash_attn<<<dim3(16, 64), 256, 0, stream>>>(Qr, Kr, Vt, ctxb);

    gemm_bt<1><<<dim3(32, 32), 256, 0, stream>>>(ctxb, Wob, out, 4096, 4096, 4096);
}

// Round 6
// 834.118 us; speedup vs baseline: 1.5097x; 1.0906x over previous
//
#include <hip/hip_runtime.h>

// Problem constants: B=2, S=2048, D_IN=D_OUT=4096, H=32, G=8, HD=128, GS=4
// All matmuls are C[M,N] = A[M,K] @ B[N,K]^T ("gemm_bt", K contiguous in both).

typedef float f32x4 __attribute__((ext_vector_type(4)));
typedef short s16x8 __attribute__((ext_vector_type(8)));

union U8 { s16x8 v; unsigned int u[4]; };

__device__ __forceinline__ unsigned short f32_to_bf16(float f) {
    unsigned int u = __float_as_uint(f);
    u += 0x7fffu + ((u >> 16) & 1u);   // round-to-nearest-even
    return (unsigned short)(u >> 16);
}
__device__ __forceinline__ float bf16_to_f32(unsigned short h) {
    return __uint_as_float(((unsigned int)h) << 16);
}
// packed f32->bf16 pair: lo16 = cvt(a), hi16 = cvt(b)
__device__ __forceinline__ unsigned int cvt_pk_bf16(float a, float b) {
    unsigned int r;
    asm("v_cvt_pk_bf16_f32 %0, %1, %2" : "=v"(r) : "v"(a), "v"(b));
    return r;
}
// async global->LDS, 16B per lane. LDS dest is wave-uniform base + lane*16.
__device__ __forceinline__ void async16(const unsigned short* g, unsigned short* l) {
    __builtin_amdgcn_global_load_lds(
        (const __attribute__((address_space(1))) unsigned int*)g,
        (__attribute__((address_space(3))) unsigned int*)l, 16, 0, 0);
}

// ---------------- fp32 -> bf16 cast ----------------
__global__ __launch_bounds__(256) void cast_f32_bf16(
    const float* __restrict__ in, unsigned short* __restrict__ out, int n4)
{
    int idx = blockIdx.x * 256 + threadIdx.x;
    if (idx >= n4) return;
    float4 v = ((const float4*)in)[idx];
    ushort4 o;
    o.x = f32_to_bf16(v.x); o.y = f32_to_bf16(v.y);
    o.z = f32_to_bf16(v.z); o.w = f32_to_bf16(v.w);
    ((ushort4*)out)[idx] = o;
}

// ---------------- bf16 gemm_bt: C = A[M,K] * B[N,K]^T ----------------
// 128x128 tile, BK=32, 256 thr / 4 waves, each wave 64x64 (4x4 MFMA tiles).
// Double-buffered LDS: ONE __syncthreads per K-step, tile kt+1's loads
// issued right after it and given the whole compute phase to land.
// Chunk swizzle quad^((row>>1)&3): 2-way LDS access (free); 0 conflicts
// measured (was 1.678e7 at 4-way with quad^(row&3)).
template<int WRITE_F32>
__global__ __launch_bounds__(256) void gemm_bt(
    const unsigned short* __restrict__ A,
    const unsigned short* __restrict__ B,
    void* __restrict__ Cout, int M, int N, int K)
{
    __shared__ __attribute__((aligned(16))) unsigned short sA[2][128*32];
    __shared__ __attribute__((aligned(16))) unsigned short sB[2][128*32];
    const int tid  = threadIdx.x;
    const int lane = tid & 63;
    const int wv   = tid >> 6;
    const int wm   = (wv >> 1) * 64;
    const int wn   = (wv & 1) * 64;
    const int quad = lane >> 4;
    const int lr   = lane & 15;
    const int m0 = blockIdx.y * 128;
    const int n0 = blockIdx.x * 128;

    auto stage = [&](int kt, int bi) {
        const int k0 = kt << 5;
        #pragma unroll
        for (int p = 0; p < 2; ++p) {
            int e  = (p*256 + tid) * 8;
            int r  = e >> 5;                  // tile-local row 0..127
            int cc = (e & 31) >> 3;           // phys chunk 0..3
            int gc = (cc ^ ((r >> 1) & 3)) * 8;  // swizzled logical col
            async16(&A[(size_t)(m0 + r)*K + k0 + gc], &sA[bi][e]);
            async16(&B[(size_t)(n0 + r)*K + k0 + gc], &sB[bi][e]);
        }
    };

    f32x4 acc[4][4] = {};
    const int nkt = K >> 5;
    stage(0, 0);
    for (int kt = 0; kt < nkt; ++kt) {
        const int buf = kt & 1;
        __syncthreads();                     // tile kt landed; buf^1 readers done
        if (kt + 1 < nkt) stage(kt + 1, buf ^ 1);
        s16x8 af[4], bf[4];
        #pragma unroll
        for (int i = 0; i < 4; ++i) {
            int row = wm + i*16 + lr;
            af[i] = *(const s16x8*)&sA[buf][row*32 + ((quad ^ ((row >> 1) & 3)) * 8)];
        }
        #pragma unroll
        for (int j = 0; j < 4; ++j) {
            int row = wn + j*16 + lr;
            bf[j] = *(const s16x8*)&sB[buf][row*32 + ((quad ^ ((row >> 1) & 3)) * 8)];
        }
        #pragma unroll
        for (int i = 0; i < 4; ++i)
            #pragma unroll
            for (int j = 0; j < 4; ++j)
                acc[i][j] = __builtin_amdgcn_mfma_f32_16x16x32_bf16(af[i], bf[j], acc[i][j], 0, 0, 0);
    }
    // C/D layout: col = lane&15, row = (lane>>4)*4 + reg  (m89/m91 verified)
    #pragma unroll
    for (int i = 0; i < 4; ++i) {
        #pragma unroll
        for (int j = 0; j < 4; ++j) {
            #pragma unroll
            for (int r = 0; r < 4; ++r) {
                size_t row = (size_t)(m0 + wm + i*16 + quad*4 + r);
                size_t col = (size_t)(n0 + wn + j*16 + lr);
                float v = acc[i][j][r];
                if (WRITE_F32) ((float*)Cout)[row*(size_t)N + col] = v;
                else ((unsigned short*)Cout)[row*(size_t)N + col] = f32_to_bf16(v);
            }
        }
    }
}

// ---------------- RoPE + [B*S, rowstride] -> [B,NH,S,128] ----------------
// oscale folds the attention scale (1/sqrt(128)*log2e) into Q; 1.0 for K.
template<int NHEADS>
__global__ __launch_bounds__(256) void rope_rearrange(
    const unsigned short* __restrict__ in, unsigned short* __restrict__ out,
    int rowstride, float oscale)
{
    constexpr int LH = (NHEADS == 32) ? 5 : 3;
    int idx = blockIdx.x * 256 + threadIdx.x;
    int i  = idx & 63;
    int hh = (idx >> 6) & (NHEADS - 1);
    int s  = (idx >> (6 + LH)) & 2047;
    int b  = idx >> (17 + LH);
    size_t inoff = (size_t)(b*2048 + s) * rowstride + hh*128 + i;
    float x1 = bf16_to_f32(in[inoff]);
    float x2 = bf16_to_f32(in[inoff + 64]);
    float freq = expf((float)i * -0.14391156831212787f);  // ln(10000)/64
    float ang  = (float)s * freq;
    float sn, cs;
    sincosf(ang, &sn, &cs);
    size_t outoff = ((size_t)(b*NHEADS + hh) * 2048 + s) * 128 + i;
    out[outoff]      = f32_to_bf16((x1*cs - x2*sn) * oscale);
    out[outoff + 64] = f32_to_bf16((x2*cs + x1*sn) * oscale);
}

// ---------------- V: KVlin[B*S, 2048] (cols 1024+) -> Vt [B,G,128,2048] ----
// LDS tile transpose: per block one (b,g) x 128-s tile.
// Output columns are PERMUTED within each 64-s block so that flash's packed
// K=32 PV fragment (kv = c*32 + sub16*16 + quad*4 + j0) is one contiguous
// 16B chunk: stored position p holds s-offset
//   g(p) = (p>>5)*32 + ((p>>2)&1)*16 + ((p>>3)&3)*4 + (p&3).
__global__ __launch_bounds__(256) void rearrange_vt(
    const unsigned short* __restrict__ in, unsigned short* __restrict__ out)
{
    __shared__ __attribute__((aligned(16))) unsigned short sS[128*136];
    const int tid = threadIdx.x;
    const int bg  = blockIdx.y;
    const int b   = bg >> 3, g = bg & 7;
    const int s0  = blockIdx.x * 128;
    // phase 1: load 128s x 128d coalesced, store to LDS [s][d] (pad 136)
    #pragma unroll
    for (int p = 0; p < 8; ++p) {
        int ce = p*256 + tid;          // chunk: s = ce>>4, dc = ce&15
        int s  = ce >> 4, dc = ce & 15;
        s16x8 v = *(const s16x8*)&in[(size_t)(b*2048 + s0 + s)*2048 + 1024 + g*128 + dc*8];
        *(s16x8*)&sS[s*136 + dc*8] = v;
    }
    __syncthreads();
    // phase 2: write out rows d, permuted-contiguous along s
    const int d    = tid & 127;
    const int half = tid >> 7;
    const size_t obase = ((size_t)(bg)*128 + d)*2048 + s0;
    #pragma unroll
    for (int i = 0; i < 8; ++i) {
        int sc   = half*8 + i;         // output 8-short chunk index 0..15
        int blk  = sc >> 3;            // which 64-block of the 128 tile
        int base = (sc & 7) * 8;       // position within 64-block
        s16x8 ov;
        #pragma unroll
        for (int j = 0; j < 8; ++j) {
            int p = base + j;
            int soff = blk*64 + ((p >> 5) << 5) + (((p >> 2) & 1) << 4)
                     + (((p >> 3) & 3) << 2) + (p & 3);
            ov[j] = (short)sS[soff*136 + d];
        }
        *(s16x8*)&out[obase + sc*8] = ov;
    }
}

// ---------------- flash attention v2 (S^T trick, 32 q-rows/wave) ----------
// LOAD-BALANCED: grid (8, B*H); each WG processes TWO q-blocks,
// qbi = 15-bx then qbi = bx, so every WG does exactly
// (2(15-bx)+2)+(2bx+2) = 34 kv-tiles. 512 uniform blocks all co-resident
// (<= 256 CUs x 3 at 48KB LDS) -> no dispatch tail (round-5's 11.6%
// time-avg occupancy was tail idle: 16x per-block work variance).
// KV tiles of 64. K double-buffered (32KB) + Vt SINGLE-buffered (16KB).
// launch_bounds(256,2): NOT reg-capped (the (256,3) cap spilled ~50 regs).
// Two-barrier schedule, per-wave counted vmcnt:
//   top:  vmcnt(0) [only K(kt)'s 4 loads outstanding] + barrier
//         -> K(kt) visible to all AND all waves done with PV(kt-1) (sVt WAR)
//   stage Vt(kt) then K(kt+1) (order pinned; vmcnt counting exact)
//   QK + softmax cover Vt's HBM latency
//   vmcnt(4) + barrier -> Vt landed everywhere; K(kt+1) stays in flight
//   PV
// QK^T computed TRANSPOSED (A=K, B=Q): S^T C-layout col=lane&15=q,
// row=quad*4+r=kv. PV packs TWO 16-kv sub-tiles into one dense K=32 MFMA:
// A-frag j=0..3 <- p[2c], j=4..7 <- p[2c+1]; the matching V fragment is one
// contiguous b128 thanks to rearrange_vt's column permutation (verified r2).
// Q pre-scaled by 1/sqrt(128)*log2e. Defer-max (THR=8): skip O-rescale
// unless per-row max grew >8; l cross-lane reduction deferred to epilogue.
__global__ __launch_bounds__(256, 2) void flash_attn(
    const unsigned short* __restrict__ Q,    // [B,H,S,128] (pre-scaled)
    const unsigned short* __restrict__ K,    // [B,G,S,128]
    const unsigned short* __restrict__ Vt,   // [B,G,128,S] (col-permuted)
    unsigned short* __restrict__ ctx)        // [B*S, H*128]
{
    __shared__ __attribute__((aligned(16))) unsigned short sK[2][64*128];  // 32KB
    __shared__ __attribute__((aligned(16))) unsigned short sVt[128*64];    // 16KB

    const int tid  = threadIdx.x;
    const int lane = tid & 63;
    const int w    = tid >> 6;
    const int quad = lane >> 4;
    const int lr   = lane & 15;
    const int bx = blockIdx.x;               // 0..7
    const int b  = blockIdx.y >> 5;
    const int h  = blockIdx.y & 31;
    const int g  = h >> 2;

    const size_t kvbase = (size_t)(b*8 + g) * 2048 * 128;
    const size_t vtbase = (size_t)(b*8 + g) * 128 * 2048;

    auto stageK = [&](int kt, int bi) {
        const size_t kbase = kvbase + (size_t)kt*64*128;
        #pragma unroll
        for (int p = 0; p < 4; ++p) {                 // K: async, swizzled
            int e = (p*256 + tid) * 8;
            int r = e >> 7;
            int s = (e & 127) >> 3;
            int gsrc = (s ^ (r & 15)) * 8;
            async16(&K[kbase + (size_t)r*128 + gsrc], &sK[bi][e]);
        }
    };
    auto stageV = [&](int kt) {
        #pragma unroll
        for (int p = 0; p < 4; ++p) {                 // Vt: async, swizzled
            int ce = p*256 + tid;                     // d = ce>>3, c = ce&7
            int d  = ce >> 3;
            int c  = ce & 7;
            int gc = (c ^ (d & 7)) * 8;
            async16(&Vt[vtbase + (size_t)d*2048 + kt*64 + gc], &sVt[ce*8]);
        }
    };

    for (int hf = 0; hf < 2; ++hf) {
        const int qbi = hf ? bx : (15 - bx); // heavy half first
        const int q0 = qbi * 128;
        const int qw0 = q0 + w * 32;         // wave's first q-row
        const int KT = 2*qbi + 2;            // kv tiles for this q-block

        s16x8 qf[2][4];                      // B-frag: n=q=lane&15, k=d=quad*8+j
        #pragma unroll
        for (int qt = 0; qt < 2; ++qt) {
            const size_t qrow = ((size_t)(b*32 + h) * 2048 + qw0 + qt*16 + lr) * 128;
            #pragma unroll
            for (int kc = 0; kc < 4; ++kc)
                qf[qt][kc] = *(const s16x8*)&Q[qrow + kc*32 + quad*8];
        }

        float m_[2] = {-1e30f, -1e30f};
        float l_[2] = {0.f, 0.f};            // per-quad partial; reduced at end
        f32x4 o[2][8] = {};

        stageK(0, 0);
        for (int kt = 0; kt < KT; ++kt) {
            const int buf = kt & 1;
            // K(kt) are this wave's only outstanding loads here (plus qf
            // globals / prior epilogue stores at kt=0 -- draining harmless).
            asm volatile("s_waitcnt vmcnt(0)" ::: "memory");
            __builtin_amdgcn_s_barrier();    // K(kt) in LDS; PV(kt-1) done (sVt WAR)
            __builtin_amdgcn_sched_barrier(0);
            stageV(kt);                      // issue Vt(kt) first (oldest 4)
            __builtin_amdgcn_sched_barrier(0);   // pin V-before-K issue order
            if (kt + 1 < KT) stageK(kt + 1, buf ^ 1);
            __builtin_amdgcn_sched_barrier(0);

            const bool act = (kt*64 <= qw0 + 31);     // wave has visible kv
            const bool v0  = (kt*64 <= qw0 + 15);     // qt=0 sub-tile visible
            U8 pa[2][2];
            if (act) {
                f32x4 sacc[2][4] = {};       // S^T tiles: [qt][ct]
                __builtin_amdgcn_s_setprio(1);
                #pragma unroll
                for (int ct = 0; ct < 4; ++ct) {
                    int row = ct*16 + lr;    // kv-local (A m-index)
                    #pragma unroll
                    for (int kc = 0; kc < 4; ++kc) {
                        s16x8 kf = *(const s16x8*)&sK[buf][row*128 + (((kc*4 + quad) ^ lr)*8)];
                        if (v0) sacc[0][ct] = __builtin_amdgcn_mfma_f32_16x16x32_bf16(kf, qf[0][kc], sacc[0][ct], 0, 0, 0);
                        sacc[1][ct] = __builtin_amdgcn_mfma_f32_16x16x32_bf16(kf, qf[1][kc], sacc[1][ct], 0, 0, 0);
                    }
                }
                __builtin_amdgcn_s_setprio(0);
                #pragma unroll
                for (int qt = 0; qt < 2; ++qt) {
                    if (qt == 0 && !v0) continue;
                    const int qbase = qw0 + qt*16;
                    const bool anymask = (kt*64 + 63) > qbase;
                    const int qg = qbase + lr;   // this lane's q-row
                    float p[4][4];
                    float vmax = -1e30f;
                    #pragma unroll
                    for (int ct = 0; ct < 4; ++ct)
                        #pragma unroll
                        for (int r = 0; r < 4; ++r) {
                            float sv = sacc[qt][ct][r];
                            if (anymask) {
                                int kv = kt*64 + ct*16 + quad*4 + r;
                                if (kv > qg) sv = -1e30f;
                            }
                            p[ct][r] = sv;
                            vmax = fmaxf(vmax, sv);
                        }
                    vmax = fmaxf(vmax, __shfl_xor(vmax, 16));
                    vmax = fmaxf(vmax, __shfl_xor(vmax, 32));
                    float mcur;
                    if (__any(vmax > m_[qt] + 8.f)) {     // rare: rescale needed
                        float mnew = fmaxf(m_[qt], vmax);
                        float alpha = exp2f(m_[qt] - mnew);
                        m_[qt] = mnew;
                        mcur = mnew;
                        l_[qt] *= alpha;
                        f32x4 av;            // alpha per O-row q=quad*4+r
                        #pragma unroll
                        for (int r = 0; r < 4; ++r)
                            av[r] = __shfl(alpha, quad*4 + r);
                        #pragma unroll
                        for (int t = 0; t < 8; ++t)
                            o[qt][t] = o[qt][t] * av;
                    } else {
                        mcur = m_[qt];       // defer: P bounded by 2^8
                    }
                    float rs = 0.f;
                    #pragma unroll
                    for (int ct = 0; ct < 4; ++ct)
                        #pragma unroll
                        for (int r = 0; r < 4; ++r) {
                            float pv = exp2f(p[ct][r] - mcur);
                            p[ct][r] = pv;
                            rs += pv;
                        }
                    l_[qt] += rs;            // quad-partial; reduced in epilogue
                    // pack P -> dense K=32 A-frags (j=0..3 <- 2c, j=4..7 <- 2c+1)
                    pa[qt][0].u[0] = cvt_pk_bf16(p[0][0], p[0][1]);
                    pa[qt][0].u[1] = cvt_pk_bf16(p[0][2], p[0][3]);
                    pa[qt][0].u[2] = cvt_pk_bf16(p[1][0], p[1][1]);
                    pa[qt][0].u[3] = cvt_pk_bf16(p[1][2], p[1][3]);
                    pa[qt][1].u[0] = cvt_pk_bf16(p[2][0], p[2][1]);
                    pa[qt][1].u[1] = cvt_pk_bf16(p[2][2], p[2][3]);
                    pa[qt][1].u[2] = cvt_pk_bf16(p[3][0], p[3][1]);
                    pa[qt][1].u[3] = cvt_pk_bf16(p[3][2], p[3][3]);
                }
            }
            // Vt(kt) landed for ALL waves; K(kt+1)'s 4 loads stay in flight.
            if (kt + 1 < KT) asm volatile("s_waitcnt vmcnt(4)" ::: "memory");
            else             asm volatile("s_waitcnt vmcnt(0)" ::: "memory");
            __builtin_amdgcn_s_barrier();
            __builtin_amdgcn_sched_barrier(0);
            if (act) {
                const int dk = lr & 7;
                __builtin_amdgcn_s_setprio(1);
                #pragma unroll
                for (int t = 0; t < 8; ++t) {    // O += P V (dense K=32)
                    const int d = t*16 + lr;
                    #pragma unroll
                    for (int c = 0; c < 2; ++c) {
                        s16x8 v8 = *(const s16x8*)&sVt[d*64 + (((c*4 + quad) ^ dk)*8)];
                        if (v0) o[0][t] = __builtin_amdgcn_mfma_f32_16x16x32_bf16(pa[0][c].v, v8, o[0][t], 0, 0, 0);
                        o[1][t] = __builtin_amdgcn_mfma_f32_16x16x32_bf16(pa[1][c].v, v8, o[1][t], 0, 0, 0);
                    }
                }
                __builtin_amdgcn_s_setprio(0);
            }
        }
        #pragma unroll
        for (int qt = 0; qt < 2; ++qt) {
            float lt = l_[qt];
            lt += __shfl_xor(lt, 16);        // deferred cross-quad reduction
            lt += __shfl_xor(lt, 32);
            f32x4 lv;
            #pragma unroll
            for (int r = 0; r < 4; ++r)
                lv[r] = __shfl(lt, quad*4 + r);
            #pragma unroll
            for (int r = 0; r < 4; ++r) {
                float inv = 1.0f / lv[r];
                int q = q0 + w*32 + qt*16 + quad*4 + r;
                size_t obase = ((size_t)b*2048 + q) * 4096 + h*128;
                #pragma unroll
                for (int t = 0; t < 8; ++t)
                    ctx[obase + t*16 + lr] = f32_to_bf16(o[qt][t][r] * inv);
            }
        }
    }
}

extern "C" void kernel_launch(void* const* d_in, const int* in_sizes, int n_in,
                              void* d_out, int out_size, void* d_ws, size_t ws_size,
                              hipStream_t stream)
{
    const float* x  = (const float*)d_in[0];
    const float* Wq = (const float*)d_in[1];
    const float* Wk = (const float*)d_in[2];
    const float* Wv = (const float*)d_in[3];
    const float* Wo = (const float*)d_in[4];
    float* out = (float*)d_out;
    char* ws = (char*)d_ws;

    // workspace layout (184,549,376 B total)
    unsigned short* xb    = (unsigned short*)(ws);              // 33.5 MB
    unsigned short* Wqb   = (unsigned short*)(ws + 33554432);   // 33.5 MB
    unsigned short* Wkvb  = (unsigned short*)(ws + 67108864);   // 16.8 MB (K rows 0..1023, V rows 1024..2047)
    unsigned short* Wob   = (unsigned short*)(ws + 83886080);   // 33.5 MB
    unsigned short* Qlin  = (unsigned short*)(ws + 117440512);  // 33.5 MB
    unsigned short* KVlin = (unsigned short*)(ws + 150994944);  // 16.8 MB [B*S, 2048]
    unsigned short* Kr    = (unsigned short*)(ws + 167772160);  //  8.4 MB
    unsigned short* Vt    = (unsigned short*)(ws + 176160768);  //  8.4 MB [B,G,128,S]
    unsigned short* Qr    = xb;    // alias: xb dead after QKV GEMMs
    unsigned short* ctxb  = Qlin;  // alias: Qlin dead after rope

    cast_f32_bf16<<<16384, 256, 0, stream>>>(x,  xb,  4194304);
    cast_f32_bf16<<<16384, 256, 0, stream>>>(Wq, Wqb, 4194304);
    cast_f32_bf16<<<4096,  256, 0, stream>>>(Wk, Wkvb,           1048576);
    cast_f32_bf16<<<4096,  256, 0, stream>>>(Wv, Wkvb + 4194304, 1048576);
    cast_f32_bf16<<<16384, 256, 0, stream>>>(Wo, Wob, 4194304);

    gemm_bt<0><<<dim3(32, 32), 256, 0, stream>>>(xb, Wqb,  Qlin,  4096, 4096, 4096);
    gemm_bt<0><<<dim3(16, 32), 256, 0, stream>>>(xb, Wkvb, KVlin, 4096, 2048, 4096);

    // Q pre-scaled by 1/sqrt(128)*log2(e); K unscaled.
    rope_rearrange<32><<<32768, 256, 0, stream>>>(Qlin,  Qr, 4096, 0.12751646f);
    rope_rearrange<8><<<8192,   256, 0, stream>>>(KVlin, Kr, 2048, 1.0f);
    rearrange_vt<<<dim3(16, 16), 256, 0, stream>>>(KVlin, Vt);

    flash_attn<<<dim3(8, 64), 256, 0, stream>>>(Qr, Kr, Vt, ctxb);

    gemm_bt<1><<<dim3(32, 32), 256, 0, stream>>>(ctxb, Wob, out, 4096, 4096, 4096);
}